// Round 4
// baseline (242.947 us; speedup 1.0000x reference)
//
#include <hip/hip_runtime.h>
#include <math.h>

#define B_    256
#define C_    22
#define T_    1000
#define NB_   6
#define E_    6
#define MNB_  48
#define POOL_ 125
#define TP_   8
#define NC_   9
#define FEAT_ 384   // MNB_*TP_

#define PQ_   352    // plane length (phys q index 0..351); data at phys 8..341

// x accessor on the 3-phase plane layout: XAT(m) == x[m] (zeros in halos),
// valid for m in [-24, 1031]. phys = (m+24)/3, plane = (m+24)%3.
#define XAT(m) bw[((m)+24)%3][((m)+24)/3]

// One plane-pass of the fused 29-tap kernel: 4 aligned float4 reads from
// plane pp at base 4*tid+Aoff, taps ck[j0+3a], output o uses f[idx0+a+o].
#define PLANE_PASS(pp, Aoff, idx0, j0, nj)                                   \
    {                                                                        \
        const float4* pb = (const float4*)&bw[pp][4*tid + (Aoff)];           \
        float4 g0 = pb[0], g1 = pb[1], g2 = pb[2], g3 = pb[3];               \
        float f[16] = {g0.x,g0.y,g0.z,g0.w, g1.x,g1.y,g1.z,g1.w,             \
                       g2.x,g2.y,g2.z,g2.w, g3.x,g3.y,g3.z,g3.w};            \
        _Pragma("unroll")                                                    \
        for (int a = 0; a < (nj); ++a) {                                     \
            const float cj = ck[(j0) + 3*a];                                 \
            s0 = fmaf(cj, f[(idx0) + a    ], s0);                            \
            s1 = fmaf(cj, f[(idx0) + a + 1], s1);                            \
            s2 = fmaf(cj, f[(idx0) + a + 2], s2);                            \
            s3 = fmaf(cj, f[(idx0) + a + 3], s3);                            \
        }                                                                    \
    }

// ---------------------------------------------------------------------------
// Stage 1 (fused, phase-split LDS): 29-tap combined FIR+conv kernel, BN,
// ReLU, sconv-accum, pooled hp (B,NB,8) and gate-mean gm (B,NB).
// One block per (b, nb); 256 threads; thread owns t0=4*tid..t0+3.
// x row stored as 3 deinterleaved planes (plane[p][q] = x[3q+p]) so window
// reads are 16B-lane-stride ds_read_b128 (conflict-light). 1 barrier/channel.
// ---------------------------------------------------------------------------
__global__ __launch_bounds__(256, 2) void fb_stage1(
    const float* __restrict__ x,
    const float* __restrict__ fir,
    const float* __restrict__ w3,
    const float* __restrict__ w5,
    const float* __restrict__ w7,
    const float* __restrict__ bn_g, const float* __restrict__ bn_b,
    const float* __restrict__ bn_m, const float* __restrict__ bn_v,
    const float* __restrict__ sconv_w,
    float* __restrict__ hp, float* __restrict__ gm)
{
    const int b   = blockIdx.x / NB_;
    const int nb  = blockIdx.x % NB_;
    const int tid = threadIdx.x;

    __shared__ float pl[2][3][PQ_];   // double-buffered 3-phase planes
    __shared__ float hrow[1000];
    __shared__ float firs[21];
    __shared__ float w3s[3], w5s[5], w7s[7];
    __shared__ float sws[22];
    __shared__ float sbn[2];
    __shared__ float psum[8];

    if (tid < 21)                 firs[tid]    = fir[nb*21 + tid];
    if (tid >= 32  && tid < 35)   w3s[tid-32]  = w3[nb*3 + (tid-32)];
    if (tid >= 64  && tid < 69)   w5s[tid-64]  = w5[nb*5 + (tid-64)];
    if (tid >= 96  && tid < 103)  w7s[tid-96]  = w7[nb*7 + (tid-96)];
    if (tid >= 128 && tid < 150)  sws[tid-128] = sconv_w[nb*C_ + (tid-128)];
    if (tid == 160) {
        float sc = bn_g[nb] * rsqrtf(bn_v[nb] + 1e-5f);
        sbn[0] = sc * (1.f/3.f);                 // folds the /3 of triple-mean
        sbn[1] = bn_b[nb] - bn_m[nb] * sc;
    }
    // Zero halos once: phys [0..7] and [341..351] on all planes, both buffers,
    // EXCEPT (plane0, phys341) which is data (x[999], rewritten every channel).
    if (tid < 114) {
        const int b2  = tid / 57;
        const int rem = tid % 57;
        const int p   = rem / 19;
        const int s   = rem % 19;
        const int ph  = (s < 8) ? s : (333 + s);          // 0..7, 341..351
        if (!(p == 0 && ph == 341)) pl[b2][p][ph] = 0.f;
    }

    const bool act = (tid <= 249);
    const int  r   = (tid <= 82) ? 0 : ((tid <= 166) ? 1 : 2);

    __syncthreads();

    // Build per-thread fused 29-tap kernel ck (once): ck = conv(weff_r, fir).
    float ck[29];
    if (act) {
        float weff[9];
        const float* wk = (r == 0) ? w3s : (r == 1 ? w5s : w7s);
        const int K  = (r == 0) ? 3 : (r == 1 ? 5 : 7);
        const int pk = K >> 1;
        #pragma unroll
        for (int oi = 0; oi < 9; ++oi) {
            const int o = oi - 3;
            float s = 0.f;
            #pragma unroll
            for (int k = 0; k < 7; ++k) {
                if (k < K) {
                    int j = o + pk - k;
                    if (j >= 0 && j < 3) s += wk[k];
                }
            }
            weff[oi] = s;
        }
        #pragma unroll
        for (int j = 0; j < 29; ++j) {
            float s = 0.f;
            #pragma unroll
            for (int oi = 0; oi < 9; ++oi) {
                const int i = j - oi;
                if (i >= 0 && i < 21) s = fmaf(weff[oi], firs[i], s);
            }
            ck[j] = s;
        }
    }

    const float* xrow = x + (size_t)(b * C_) * T_;
    float4 stg = make_float4(0.f, 0.f, 0.f, 0.f);
    if (tid < 250) stg = *(const float4*)(xrow + 4*tid);

    float acc0 = 0.f, acc1 = 0.f, acc2 = 0.f, acc3 = 0.f;

    #pragma unroll 1
    for (int c = 0; c < C_; ++c) {
        float (*bw)[PQ_] = pl[c & 1];
        if (tid < 250) {
            // deinterleave 4 elements x[4tid..4tid+3] into planes
            int mm = 4*tid + 24;
            int q  = mm / 3;
            int p  = mm - 3*q;
            float v0 = stg.x, v1 = stg.y, v2 = stg.z, v3 = stg.w;
            bw[p][q] = v0; ++p; if (p == 3) { p = 0; ++q; }
            bw[p][q] = v1; ++p; if (p == 3) { p = 0; ++q; }
            bw[p][q] = v2; ++p; if (p == 3) { p = 0; ++q; }
            bw[p][q] = v3;
        }
        __syncthreads();
        if (tid < 250 && c + 1 < C_)
            stg = *(const float4*)(xrow + (size_t)(c+1)*T_ + 4*tid);

        if (act) {
            float s0 = 0.f, s1 = 0.f, s2 = 0.f, s3 = 0.f;

            if (r == 0) {
                PLANE_PASS(2, 0,   3, 0, 10)
                PLANE_PASS(0, 4,   0, 1, 10)
                PLANE_PASS(1, 4,   0, 2, 9)
            } else if (r == 1) {
                PLANE_PASS(1, -332, 2, 0, 10)
                PLANE_PASS(2, -332, 2, 1, 10)
                PLANE_PASS(0, -332, 3, 2, 9)
            } else {
                PLANE_PASS(0, -664, 1, 0, 10)
                PLANE_PASS(1, -664, 1, 1, 10)
                PLANE_PASS(2, -664, 1, 2, 9)
            }

            if (tid == 0) {
                // t=0: subtract w3[0]*xb'[-1]  (xb zero-pad of 2nd conv)
                float xbm1 = 0.f;
                #pragma unroll
                for (int i = 0; i < 21; ++i) xbm1 = fmaf(firs[i], XAT(i - 11), xbm1);
                s0 -= w3s[0] * xbm1;
            } else if (tid == 83) {
                // outputs 332,333 direct; 334,335 fused (r=1) ok
                float xb[5];                       // xb'[995..999]
                #pragma unroll
                for (int d = 0; d < 5; ++d) {
                    float s = 0.f;
                    #pragma unroll
                    for (int i = 0; i < 21; ++i) s = fmaf(firs[i], XAT(985 + d + i), s);
                    xb[d] = s;
                }
                float xb0[4];                      // xb'[0..3]
                #pragma unroll
                for (int p = 0; p < 4; ++p) {
                    float s = 0.f;
                    #pragma unroll
                    for (int i = 0; i < 21; ++i) s = fmaf(firs[i], XAT(p + i - 10), s);
                    xb0[p] = s;
                }
                s0 = w3s[0]*(xb[0]+xb[1]+xb[2]) + w3s[1]*(xb[1]+xb[2]+xb[3])
                   + w3s[2]*(xb[2]+xb[3]+xb[4]);
                s1 = w3s[0]*xb[3] + w3s[1]*xb[4]
                   + w5s[2]*xb0[0] + w5s[3]*xb0[1] + w5s[4]*xb0[2]
                   + w5s[1]*xb0[0] + w5s[2]*xb0[1] + w5s[3]*xb0[2] + w5s[4]*xb0[3];
            } else if (tid == 166) {
                // outputs 664,665 fused (r=1) ok; 666,667 direct
                float xbU[4];                      // xb'[996..999]
                #pragma unroll
                for (int p = 0; p < 4; ++p) {
                    float s = 0.f;
                    #pragma unroll
                    for (int i = 0; i < 21; ++i) s = fmaf(firs[i], XAT(986 + p + i), s);
                    xbU[p] = s;
                }
                float xb0[7];                      // xb'[0..6]
                #pragma unroll
                for (int p = 0; p < 7; ++p) {
                    float s = 0.f;
                    #pragma unroll
                    for (int i = 0; i < 21; ++i) s = fmaf(firs[i], XAT(p + i - 10), s);
                    xb0[p] = s;
                }
                s2 = w5s[0]*xbU[0] + w5s[1]*xbU[1] + w5s[2]*xbU[2] + w5s[3]*xbU[3]
                   + w5s[0]*xbU[1] + w5s[1]*xbU[2] + w5s[2]*xbU[3]
                   + w7s[3]*xb0[0] + w7s[4]*xb0[1] + w7s[5]*xb0[2] + w7s[6]*xb0[3];
                s3 = w7s[2]*xb0[0] + w7s[3]*xb0[1] + w7s[4]*xb0[2] + w7s[5]*xb0[3] + w7s[6]*xb0[4]
                   + w7s[1]*xb0[0] + w7s[2]*xb0[1] + w7s[3]*xb0[2] + w7s[4]*xb0[3] + w7s[5]*xb0[4] + w7s[6]*xb0[5]
                   + w7s[0]*xb0[0] + w7s[1]*xb0[1] + w7s[2]*xb0[2] + w7s[3]*xb0[3] + w7s[4]*xb0[4] + w7s[5]*xb0[5] + w7s[6]*xb0[6];
            } else if (tid == 249) {
                // t=999: subtract weff7-weighted FIR-extended xb'[1000..1002]
                // (R2/R3 read the wrong window here — fixed: x[990+i] etc.)
                float xbA = 0.f, xbB = 0.f, xbC = 0.f;
                #pragma unroll
                for (int i = 0; i < 21; ++i) {
                    xbA = fmaf(firs[i], XAT(990 + i), xbA);
                    xbB = fmaf(firs[i], XAT(991 + i), xbB);
                    xbC = fmaf(firs[i], XAT(992 + i), xbC);
                }
                const float we3 = w7s[4] + w7s[5] + w7s[6];
                const float we4 = w7s[5] + w7s[6];
                const float we5 = w7s[6];
                s3 -= we3*xbA + we4*xbB + we5*xbC;
            }

            const float sc3 = sbn[0], bi = sbn[1], sw = sws[c];
            acc0 += fmaxf(fmaf(s0, sc3, bi), 0.f) * sw;
            acc1 += fmaxf(fmaf(s1, sc3, bi), 0.f) * sw;
            acc2 += fmaxf(fmaf(s2, sc3, bi), 0.f) * sw;
            acc3 += fmaxf(fmaf(s3, sc3, bi), 0.f) * sw;
        }
    }

    __syncthreads();
    if (act) *(float4*)&hrow[4*tid] = make_float4(acc0, acc1, acc2, acc3);
    __syncthreads();

    if (tid < TP_) {
        float s = 0.f;
        for (int j = 0; j < POOL_; ++j) s += hrow[tid*POOL_ + j];
        psum[tid] = s;
        hp[(b*NB_ + nb)*TP_ + tid] = s * (1.f / POOL_);
    }
    __syncthreads();
    if (tid == 0) {
        float s = 0.f;
        for (int p = 0; p < TP_; ++p) s += psum[p];
        gm[b*NB_ + nb] = s * (1.f / T_);
    }
}

// ---------------------------------------------------------------------------
// Stage 2: gate (softmax + top-3 + renorm), experts + EBN + ReLU + mix,
//          FC + log_softmax.  One block (64 thr) per batch element.
// ---------------------------------------------------------------------------
__global__ __launch_bounds__(64) void fb_stage2(
    const float* __restrict__ hp, const float* __restrict__ gm,
    const float* __restrict__ gate_w, const float* __restrict__ gate_b,
    const float* __restrict__ exp_w,  const float* __restrict__ exp_b,
    const float* __restrict__ ebn_g,  const float* __restrict__ ebn_b,
    const float* __restrict__ ebn_m,  const float* __restrict__ ebn_v,
    const float* __restrict__ fc_w,   const float* __restrict__ fc_b,
    float* __restrict__ feats_out, float* __restrict__ logp_out)
{
    const int b   = blockIdx.x;
    const int tid = threadIdx.x;

    __shared__ float lg[MNB_];
    __shared__ float gsh[E_];
    __shared__ float hps[MNB_];
    __shared__ float fsh[FEAT_];
    __shared__ float lo[NC_];

    if (tid < MNB_) {
        hps[tid] = hp[b*MNB_ + tid];
        float s = gate_b[tid];
        for (int c = 0; c < NB_; ++c) s += gm[b*NB_ + c] * gate_w[tid*NB_ + c];
        lg[tid] = s;
    }
    __syncthreads();

    if (tid == 0) {
        float mx = lg[0];
        for (int i = 1; i < MNB_; ++i) mx = fmaxf(mx, lg[i]);
        for (int i = 0; i < MNB_; ++i) lg[i] = expf(lg[i] - mx);
        int i1 = 0, i2 = -1, i3 = -1;
        float b1 = -1.f, b2 = -1.f, b3 = -1.f;
        for (int i = 0; i < MNB_; ++i) if (lg[i] > b1) { b1 = lg[i]; i1 = i; }
        for (int i = 0; i < MNB_; ++i) if (i != i1 && lg[i] > b2) { b2 = lg[i]; i2 = i; }
        for (int i = 0; i < MNB_; ++i) if (i != i1 && i != i2 && lg[i] > b3) { b3 = lg[i]; i3 = i; }
        const float s3 = lg[i1] + lg[i2] + lg[i3];
        for (int j = 0; j < E_; ++j) gsh[j] = 0.f;
        if (i1 < E_) gsh[i1] = lg[i1] / s3;
        if (i2 < E_) gsh[i2] = lg[i2] / s3;
        if (i3 < E_) gsh[i3] = lg[i3] / s3;
    }
    __syncthreads();

    #pragma unroll
    for (int rr = 0; rr < FEAT_/64; ++rr) {
        const int idx = tid + rr*64;        // 0..383
        const int o = idx >> 3, p = idx & 7;
        float outv = 0.f;
        #pragma unroll
        for (int e = 0; e < E_; ++e) {
            const int eo = e*MNB_ + o;
            float acc = exp_b[eo];
            #pragma unroll
            for (int c = 0; c < NB_; ++c)
                acc += hps[c*TP_ + p] * exp_w[eo*NB_ + c];
            const float esc = ebn_g[eo] * rsqrtf(ebn_v[eo] + 1e-5f);
            float v = fmaf(acc - ebn_m[eo], esc, ebn_b[eo]);
            v = fmaxf(v, 0.f);
            outv += gsh[e] * v;
        }
        fsh[idx] = outv;
        feats_out[b*FEAT_ + idx] = outv;
    }
    __syncthreads();

    if (tid < NC_) {
        float s = fc_b[tid];
        for (int i = 0; i < FEAT_; ++i) s += fsh[i] * fc_w[tid*FEAT_ + i];
        lo[tid] = s;
    }
    __syncthreads();

    if (tid == 0) {
        float mx = lo[0];
        for (int k = 1; k < NC_; ++k) mx = fmaxf(mx, lo[k]);
        float Z = 0.f;
        for (int k = 0; k < NC_; ++k) Z += expf(lo[k] - mx);
        const float lse = mx + logf(Z);
        for (int k = 0; k < NC_; ++k) logp_out[b*NC_ + k] = lo[k] - lse;
    }
}

extern "C" void kernel_launch(void* const* d_in, const int* in_sizes, int n_in,
                              void* d_out, int out_size, void* d_ws, size_t ws_size,
                              hipStream_t stream) {
    const float* x       = (const float*)d_in[0];
    const float* fir     = (const float*)d_in[1];
    const float* w3      = (const float*)d_in[2];
    const float* w5      = (const float*)d_in[3];
    const float* w7      = (const float*)d_in[4];
    const float* bn1_g   = (const float*)d_in[5];
    const float* bn1_b   = (const float*)d_in[6];
    const float* bn1_m   = (const float*)d_in[7];
    const float* bn1_v   = (const float*)d_in[8];
    const float* sconv_w = (const float*)d_in[9];
    const float* gate_w  = (const float*)d_in[10];
    const float* gate_b  = (const float*)d_in[11];
    const float* exp_w   = (const float*)d_in[12];
    const float* exp_b   = (const float*)d_in[13];
    const float* ebn_g   = (const float*)d_in[14];
    const float* ebn_b   = (const float*)d_in[15];
    const float* ebn_m   = (const float*)d_in[16];
    const float* ebn_v   = (const float*)d_in[17];
    const float* fc_w    = (const float*)d_in[18];
    const float* fc_b    = (const float*)d_in[19];

    float* out       = (float*)d_out;
    float* feats_out = out;                     // (256, 384)
    float* logp_out  = out + B_ * FEAT_;        // (256, 9)

    float* hp  = (float*)d_ws;                  // (256, 48)
    float* gmv = hp + B_ * MNB_;                // (256, 6)

    fb_stage1<<<B_ * NB_, 256, 0, stream>>>(x, fir, w3, w5, w7,
                                            bn1_g, bn1_b, bn1_m, bn1_v,
                                            sconv_w, hp, gmv);
    fb_stage2<<<B_, 64, 0, stream>>>(hp, gmv, gate_w, gate_b,
                                     exp_w, exp_b, ebn_g, ebn_b, ebn_m, ebn_v,
                                     fc_w, fc_b, feats_out, logp_out);
}

// Round 5
// 138.970 us; speedup vs baseline: 1.7482x; 1.7482x over previous
//
#include <hip/hip_runtime.h>
#include <math.h>

#define B_    256
#define C_    22
#define T_    1000
#define NB_   6
#define E_    6
#define MNB_  48
#define POOL_ 125
#define TP_   8
#define NC_   9
#define FEAT_ 384   // MNB_*TP_

#define PQ_   352    // plane length; x[m] lives at (plane (m+24)%3, q (m+24)/3)

// One plane-pass of the fused 29-tap kernel: 4 aligned float4 reads from
// plane pp at base 4*lt+Aoff, taps ck[j0+3a], output o uses f[idx0+a+o].
#define PLANE_PASS(pp, Aoff, idx0, j0, nj)                                   \
    {                                                                        \
        const float4* pb = (const float4*)&bw[pp][4*lt + (Aoff)];            \
        float4 g0 = pb[0], g1 = pb[1], g2 = pb[2], g3 = pb[3];               \
        float f[16] = {g0.x,g0.y,g0.z,g0.w, g1.x,g1.y,g1.z,g1.w,             \
                       g2.x,g2.y,g2.z,g2.w, g3.x,g3.y,g3.z,g3.w};            \
        _Pragma("unroll")                                                    \
        for (int a = 0; a < (nj); ++a) {                                     \
            const float cj = ck[(j0) + 3*a];                                 \
            s0 = fmaf(cj, f[(idx0) + a    ], s0);                            \
            s1 = fmaf(cj, f[(idx0) + a + 1], s1);                            \
            s2 = fmaf(cj, f[(idx0) + a + 2], s2);                            \
            s3 = fmaf(cj, f[(idx0) + a + 3], s3);                            \
        }                                                                    \
    }

// ---------------------------------------------------------------------------
// Stage 1: one block per batch element b. 512 threads.
//  1. stage all 22 x rows into 3-phase LDS planes (once)
//  2. parallel boundary phase: xbv dots + 36 exact special outputs (corr)
//  3. 3 nb-pair passes: barrier-free fused 29-tap compute over 22 channels,
//     hrow write + special substitution + pooling
// ---------------------------------------------------------------------------
__global__ __launch_bounds__(512, 2) void fb_stage1(
    const float* __restrict__ x,
    const float* __restrict__ fir,
    const float* __restrict__ w3,
    const float* __restrict__ w5,
    const float* __restrict__ w7,
    const float* __restrict__ bn_g, const float* __restrict__ bn_b,
    const float* __restrict__ bn_m, const float* __restrict__ bn_v,
    const float* __restrict__ sconv_w,
    float* __restrict__ hp, float* __restrict__ gm)
{
    const int b   = blockIdx.x;
    const int tid = threadIdx.x;

    __shared__ float pl[C_][3][PQ_];     // 92.9 KB
    __shared__ float hrow[2][1000];      // 8 KB (A/B of current nb-pair)
    __shared__ float firs6[NB_][21];
    __shared__ float w3s6[NB_][3];
    __shared__ float w5s6[NB_][5];
    __shared__ float w7s6[NB_][7];
    __shared__ float sws6[NB_][C_];
    __shared__ float sbn6[NB_][2];
    __shared__ float xbv[NB_][C_][13];   // xb(0..6), xb(994..999) per (nb,c)
    __shared__ float term[NB_][6][C_];
    __shared__ float corr[NB_][6];
    __shared__ float psum[2][TP_];

    // ---- issue x loads early (T14): 22 rows * 250 float4 = 5500 items ----
    const float* xbase = x + (size_t)b * (C_ * T_);
    float4 g[11];
    #pragma unroll
    for (int k = 0; k < 11; ++k) {
        const int idx = tid + k * 512;
        if (idx < 5500) {
            const int c = idx / 250, j = idx % 250;
            g[k] = *(const float4*)(xbase + c * T_ + 4 * j);
        }
    }

    // ---- weights to LDS + halo zeroing ----
    if (tid < 126)                      { int nb=tid/21;  firs6[nb][tid%21] = fir[tid]; }
    else if (tid >= 128 && tid < 146)   { int k=tid-128;  w3s6[k/3][k%3] = w3[k]; }
    else if (tid >= 160 && tid < 190)   { int k=tid-160;  w5s6[k/5][k%5] = w5[k]; }
    else if (tid >= 192 && tid < 234)   { int k=tid-192;  w7s6[k/7][k%7] = w7[k]; }
    else if (tid >= 256 && tid < 388)   { int k=tid-256;  sws6[k/C_][k%C_] = sconv_w[k]; }
    else if (tid >= 400 && tid < 406) {
        const int nb = tid - 400;
        float sc = bn_g[nb] * rsqrtf(bn_v[nb] + 1e-5f);
        sbn6[nb][0] = sc * (1.f/3.f);          // folds the /3 of the triple-mean
        sbn6[nb][1] = bn_b[nb] - bn_m[nb] * sc;
    }
    // zero halos: per channel/plane q in {0..7} u {341..351} (19), 22*3*19=1254
    for (int idx = tid; idx < 1254; idx += 512) {
        const int c = idx / 57, rem = idx % 57;
        const int p = rem / 19, s = rem % 19;
        const int q = (s < 8) ? s : (333 + s);
        pl[c][p][q] = 0.f;
    }
    __syncthreads();

    // ---- deinterleave staged rows into planes ----
    #pragma unroll
    for (int k = 0; k < 11; ++k) {
        const int idx = tid + k * 512;
        if (idx < 5500) {
            const int c = idx / 250, j = idx % 250;
            int mm = 4 * j + 24;
            int q  = mm / 3, p = mm - 3 * q;
            const float vv[4] = {g[k].x, g[k].y, g[k].z, g[k].w};
            #pragma unroll
            for (int e2 = 0; e2 < 4; ++e2) {
                pl[c][p][q] = vv[e2];
                ++p; if (p == 3) { p = 0; ++q; }
            }
        }
    }
    __syncthreads();

    // ---- phase B: xbv[nb][c][pos] = FIR dot at m (uniform, parallel) ----
    for (int idx = tid; idx < NB_ * C_ * 13; idx += 512) {     // 1716
        const int nb  = idx / (C_ * 13);
        const int rem = idx % (C_ * 13);
        const int c   = rem / 13, pos = rem % 13;
        const int m   = (pos < 7) ? pos : (987 + pos);         // 0..6, 994..999
        int mm = m + 14;                                       // (m-10)+24
        int q  = mm / 3, p = mm - 3 * q;
        float s = 0.f;
        #pragma unroll
        for (int i = 0; i < 21; ++i) {
            s = fmaf(firs6[nb][i], pl[c][p][q], s);
            ++p; if (p == 3) { p = 0; ++q; }
        }
        xbv[nb][c][pos] = s;
    }
    __syncthreads();

    // ---- phase C: exact special outputs t in {0,332,333,666,667,999} ----
    for (int idx = tid; idx < NB_ * 6 * C_; idx += 512) {      // 792
        const int nb  = idx / (6 * C_);
        const int rem = idx % (6 * C_);
        const int tix = rem / C_, c = rem % C_;
        const float* X  = xbv[nb][c];   // X[0..6]=xb(0..6), X[7..12]=xb(994..999)
        const float* W3 = w3s6[nb];
        const float* W5 = w5s6[nb];
        const float* W7 = w7s6[nb];
        float s;
        switch (tix) {
        case 0:   // t=0: conv3 at q=0,1,2 (xb pad at -1)
            s = W3[1]*X[0]+W3[2]*X[1]
              + W3[0]*X[0]+W3[1]*X[1]+W3[2]*X[2]
              + W3[0]*X[1]+W3[1]*X[2]+W3[2]*X[3];
            break;
        case 1:   // t=332: conv3 at 996,997,998 (interior; thread83 had wrong ck)
            s = W3[0]*X[8]+W3[1]*X[9]+W3[2]*X[10]
              + W3[0]*X[9]+W3[1]*X[10]+W3[2]*X[11]
              + W3[0]*X[10]+W3[1]*X[11]+W3[2]*X[12];
            break;
        case 2:   // t=333: conv3@999(pad) + conv5@0,1(pad)
            s = W3[0]*X[11]+W3[1]*X[12]
              + W5[2]*X[0]+W5[3]*X[1]+W5[4]*X[2]
              + W5[1]*X[0]+W5[2]*X[1]+W5[3]*X[2]+W5[4]*X[3];
            break;
        case 3:   // t=666: conv5@998,999(pad) + conv7@0(pad)
            s = W5[0]*X[9]+W5[1]*X[10]+W5[2]*X[11]+W5[3]*X[12]
              + W5[0]*X[10]+W5[1]*X[11]+W5[2]*X[12]
              + W7[3]*X[0]+W7[4]*X[1]+W7[5]*X[2]+W7[6]*X[3];
            break;
        case 4:   // t=667: conv7@1,2,3 (1,2 pad)
            s = W7[2]*X[0]+W7[3]*X[1]+W7[4]*X[2]+W7[5]*X[3]+W7[6]*X[4]
              + W7[1]*X[0]+W7[2]*X[1]+W7[3]*X[2]+W7[4]*X[3]+W7[5]*X[4]+W7[6]*X[5]
              + W7[0]*X[0]+W7[1]*X[1]+W7[2]*X[2]+W7[3]*X[3]+W7[4]*X[4]+W7[5]*X[5]+W7[6]*X[6];
            break;
        default:  // t=999: conv7@997,998,999 (pad at 1000+)
            s = W7[0]*X[7]+W7[1]*X[8]+W7[2]*X[9]+W7[3]*X[10]+W7[4]*X[11]+W7[5]*X[12]
              + W7[0]*X[8]+W7[1]*X[9]+W7[2]*X[10]+W7[3]*X[11]+W7[4]*X[12]
              + W7[0]*X[9]+W7[1]*X[10]+W7[2]*X[11]+W7[3]*X[12];
            break;
        }
        const float v = fmaxf(fmaf(s, sbn6[nb][0], sbn6[nb][1]), 0.f);
        term[nb][tix][c] = v * sws6[nb][c];
    }
    __syncthreads();
    if (tid < 36) {
        const int nb = tid / 6, tix = tid % 6;
        float s = 0.f;
        for (int c = 0; c < C_; ++c) s += term[nb][tix][c];
        corr[nb][tix] = s;
    }

    // ---- main passes: 3 nb-pairs, barrier-free fused compute ----
    const int  side = tid >> 8;              // 0: nb=2w, 1: nb=2w+1
    const int  lt   = tid & 255;
    const bool act  = (lt <= 249);
    const int  r    = (lt <= 82) ? 0 : ((lt <= 166) ? 1 : 2);

    for (int w = 0; w < 3; ++w) {
        const int nb = 2 * w + side;

        float ck[29];
        if (act) {
            float weff[9];
            const float* wk = (r == 0) ? w3s6[nb] : (r == 1 ? w5s6[nb] : w7s6[nb]);
            const int K  = (r == 0) ? 3 : (r == 1 ? 5 : 7);
            const int pk = K >> 1;
            #pragma unroll
            for (int oi = 0; oi < 9; ++oi) {
                const int o = oi - 3;
                float s = 0.f;
                #pragma unroll
                for (int k = 0; k < 7; ++k) {
                    if (k < K) {
                        const int j = o + pk - k;
                        if (j >= 0 && j < 3) s += wk[k];
                    }
                }
                weff[oi] = s;
            }
            #pragma unroll
            for (int j = 0; j < 29; ++j) {
                float s = 0.f;
                #pragma unroll
                for (int oi = 0; oi < 9; ++oi) {
                    const int i = j - oi;
                    if (i >= 0 && i < 21) s = fmaf(weff[oi], firs6[nb][i], s);
                }
                ck[j] = s;
            }
        }

        float acc0 = 0.f, acc1 = 0.f, acc2 = 0.f, acc3 = 0.f;
        if (act) {
            const float sc3 = sbn6[nb][0], bi = sbn6[nb][1];
            #pragma unroll 2
            for (int c = 0; c < C_; ++c) {
                const float (*bw)[PQ_] = pl[c];
                float s0 = 0.f, s1 = 0.f, s2 = 0.f, s3 = 0.f;
                if (r == 0) {
                    PLANE_PASS(2, 0,   3, 0, 10)
                    PLANE_PASS(0, 4,   0, 1, 10)
                    PLANE_PASS(1, 4,   0, 2, 9)
                } else if (r == 1) {
                    PLANE_PASS(1, -332, 2, 0, 10)
                    PLANE_PASS(2, -332, 2, 1, 10)
                    PLANE_PASS(0, -332, 3, 2, 9)
                } else {
                    PLANE_PASS(0, -664, 1, 0, 10)
                    PLANE_PASS(1, -664, 1, 1, 10)
                    PLANE_PASS(2, -664, 1, 2, 9)
                }
                const float sw = sws6[nb][c];
                acc0 += fmaxf(fmaf(s0, sc3, bi), 0.f) * sw;
                acc1 += fmaxf(fmaf(s1, sc3, bi), 0.f) * sw;
                acc2 += fmaxf(fmaf(s2, sc3, bi), 0.f) * sw;
                acc3 += fmaxf(fmaf(s3, sc3, bi), 0.f) * sw;
            }
        }

        __syncthreads();   // (A) prior pair's pooling/gm reads complete
        if (act) *(float4*)&hrow[side][4*lt] = make_float4(acc0, acc1, acc2, acc3);
        __syncthreads();   // (B)
        if (tid < 12) {    // substitute exact special outputs
            const int nbi = tid / 6, tix = tid % 6;
            const int t = (tix == 0) ? 0 :
                          (tix <= 2) ? (331 + tix) :        // 332, 333
                          (tix <= 4) ? (663 + tix) : 999;   // 666, 667
            hrow[nbi][t] = corr[2*w + nbi][tix];
        }
        __syncthreads();   // (C)
        if (tid < 16) {    // pool 8 windows of 125 per nb
            const int nbi = tid / 8, p = tid % 8;
            float s = 0.f;
            for (int j = 0; j < POOL_; ++j) s += hrow[nbi][p*POOL_ + j];
            psum[nbi][p] = s;
            hp[(b*NB_ + 2*w + nbi)*TP_ + p] = s * (1.f / POOL_);
        }
        __syncthreads();   // (D)
        if (tid < 2) {
            float s = 0.f;
            for (int p = 0; p < TP_; ++p) s += psum[tid][p];
            gm[b*NB_ + 2*w + tid] = s * (1.f / T_);
        }
    }
}

// ---------------------------------------------------------------------------
// Stage 2: gate (softmax + top-3 + renorm), experts + EBN + ReLU + mix,
//          FC + log_softmax.  One block (64 thr) per batch element.
// ---------------------------------------------------------------------------
__global__ __launch_bounds__(64) void fb_stage2(
    const float* __restrict__ hp, const float* __restrict__ gm,
    const float* __restrict__ gate_w, const float* __restrict__ gate_b,
    const float* __restrict__ exp_w,  const float* __restrict__ exp_b,
    const float* __restrict__ ebn_g,  const float* __restrict__ ebn_b,
    const float* __restrict__ ebn_m,  const float* __restrict__ ebn_v,
    const float* __restrict__ fc_w,   const float* __restrict__ fc_b,
    float* __restrict__ feats_out, float* __restrict__ logp_out)
{
    const int b   = blockIdx.x;
    const int tid = threadIdx.x;

    __shared__ float lg[MNB_];
    __shared__ float gsh[E_];
    __shared__ float hps[MNB_];
    __shared__ float fsh[FEAT_];
    __shared__ float lo[NC_];

    if (tid < MNB_) {
        hps[tid] = hp[b*MNB_ + tid];
        float s = gate_b[tid];
        for (int c = 0; c < NB_; ++c) s += gm[b*NB_ + c] * gate_w[tid*NB_ + c];
        lg[tid] = s;
    }
    __syncthreads();

    if (tid == 0) {
        float mx = lg[0];
        for (int i = 1; i < MNB_; ++i) mx = fmaxf(mx, lg[i]);
        for (int i = 0; i < MNB_; ++i) lg[i] = expf(lg[i] - mx);
        int i1 = 0, i2 = -1, i3 = -1;
        float b1 = -1.f, b2 = -1.f, b3 = -1.f;
        for (int i = 0; i < MNB_; ++i) if (lg[i] > b1) { b1 = lg[i]; i1 = i; }
        for (int i = 0; i < MNB_; ++i) if (i != i1 && lg[i] > b2) { b2 = lg[i]; i2 = i; }
        for (int i = 0; i < MNB_; ++i) if (i != i1 && i != i2 && lg[i] > b3) { b3 = lg[i]; i3 = i; }
        const float s3 = lg[i1] + lg[i2] + lg[i3];
        for (int j = 0; j < E_; ++j) gsh[j] = 0.f;
        if (i1 < E_) gsh[i1] = lg[i1] / s3;
        if (i2 < E_) gsh[i2] = lg[i2] / s3;
        if (i3 < E_) gsh[i3] = lg[i3] / s3;
    }
    __syncthreads();

    #pragma unroll
    for (int rr = 0; rr < FEAT_/64; ++rr) {
        const int idx = tid + rr*64;        // 0..383
        const int o = idx >> 3, p = idx & 7;
        float outv = 0.f;
        #pragma unroll
        for (int e = 0; e < E_; ++e) {
            const int eo = e*MNB_ + o;
            float acc = exp_b[eo];
            #pragma unroll
            for (int c = 0; c < NB_; ++c)
                acc += hps[c*TP_ + p] * exp_w[eo*NB_ + c];
            const float esc = ebn_g[eo] * rsqrtf(ebn_v[eo] + 1e-5f);
            float v = fmaf(acc - ebn_m[eo], esc, ebn_b[eo]);
            v = fmaxf(v, 0.f);
            outv += gsh[e] * v;
        }
        fsh[idx] = outv;
        feats_out[b*FEAT_ + idx] = outv;
    }
    __syncthreads();

    if (tid < NC_) {
        float s = fc_b[tid];
        for (int i = 0; i < FEAT_; ++i) s += fsh[i] * fc_w[tid*FEAT_ + i];
        lo[tid] = s;
    }
    __syncthreads();

    if (tid == 0) {
        float mx = lo[0];
        for (int k = 1; k < NC_; ++k) mx = fmaxf(mx, lo[k]);
        float Z = 0.f;
        for (int k = 0; k < NC_; ++k) Z += expf(lo[k] - mx);
        const float lse = mx + logf(Z);
        for (int k = 0; k < NC_; ++k) logp_out[b*NC_ + k] = lo[k] - lse;
    }
}

extern "C" void kernel_launch(void* const* d_in, const int* in_sizes, int n_in,
                              void* d_out, int out_size, void* d_ws, size_t ws_size,
                              hipStream_t stream) {
    const float* x       = (const float*)d_in[0];
    const float* fir     = (const float*)d_in[1];
    const float* w3      = (const float*)d_in[2];
    const float* w5      = (const float*)d_in[3];
    const float* w7      = (const float*)d_in[4];
    const float* bn1_g   = (const float*)d_in[5];
    const float* bn1_b   = (const float*)d_in[6];
    const float* bn1_m   = (const float*)d_in[7];
    const float* bn1_v   = (const float*)d_in[8];
    const float* sconv_w = (const float*)d_in[9];
    const float* gate_w  = (const float*)d_in[10];
    const float* gate_b  = (const float*)d_in[11];
    const float* exp_w   = (const float*)d_in[12];
    const float* exp_b   = (const float*)d_in[13];
    const float* ebn_g   = (const float*)d_in[14];
    const float* ebn_b   = (const float*)d_in[15];
    const float* ebn_m   = (const float*)d_in[16];
    const float* ebn_v   = (const float*)d_in[17];
    const float* fc_w    = (const float*)d_in[18];
    const float* fc_b    = (const float*)d_in[19];

    float* out       = (float*)d_out;
    float* feats_out = out;                     // (256, 384)
    float* logp_out  = out + B_ * FEAT_;        // (256, 9)

    float* hp  = (float*)d_ws;                  // (256, 48)
    float* gmv = hp + B_ * MNB_;                // (256, 6)

    fb_stage1<<<B_, 512, 0, stream>>>(x, fir, w3, w5, w7,
                                      bn1_g, bn1_b, bn1_m, bn1_v,
                                      sconv_w, hp, gmv);
    fb_stage2<<<B_, 64, 0, stream>>>(hp, gmv, gate_w, gate_b,
                                     exp_w, exp_b, ebn_g, ebn_b, ebn_m, ebn_v,
                                     fc_w, fc_b, feats_out, logp_out);
}

// Round 6
// 76.426 us; speedup vs baseline: 3.1788x; 1.8184x over previous
//
#include <hip/hip_runtime.h>
#include <math.h>

#define B_    256
#define C_    22
#define T_    1000
#define NB_   6
#define E_    6
#define MNB_  48
#define POOL_ 125
#define TP_   8
#define NC_   9
#define FEAT_ 384   // MNB_*TP_

#define PQ_   352    // plane length; x[m] lives at (plane (m+24)%3, q (m+24)/3)
#define NTH   768

// Load 4 aligned float4 (16 floats) from plane pp at element base 4*lt+Aoff.
#define LOADP(F, pp, Aoff)                                                   \
    {                                                                        \
        const float4* pb = (const float4*)&bw[pp][4*lt + (Aoff)];            \
        float4 q0 = pb[0], q1 = pb[1], q2 = pb[2], q3 = pb[3];               \
        *(float4*)&F[0]  = q0; *(float4*)&F[4]  = q1;                        \
        *(float4*)&F[8]  = q2; *(float4*)&F[12] = q3;                        \
    }

// Apply taps of BOTH nb of the pair to window F.
#define TAPS(F, idx0, j0, nj)                                                \
    _Pragma("unroll")                                                        \
    for (int a = 0; a < (nj); ++a) {                                         \
        const float ca = ckA[(j0) + 3*a];                                    \
        const float cb = ckB[(j0) + 3*a];                                    \
        sa0 = fmaf(ca, F[(idx0) + a    ], sa0);                              \
        sa1 = fmaf(ca, F[(idx0) + a + 1], sa1);                              \
        sa2 = fmaf(ca, F[(idx0) + a + 2], sa2);                              \
        sa3 = fmaf(ca, F[(idx0) + a + 3], sa3);                              \
        sb0 = fmaf(cb, F[(idx0) + a    ], sb0);                              \
        sb1 = fmaf(cb, F[(idx0) + a + 1], sb1);                              \
        sb2 = fmaf(cb, F[(idx0) + a + 2], sb2);                              \
        sb3 = fmaf(cb, F[(idx0) + a + 3], sb3);                              \
    }

// Build the fused 29-tap kernel for band NB into local array CK (r-region rr).
#define BUILD_CK(CK, NB)                                                     \
    {                                                                        \
        float weff[9];                                                       \
        const float* wk = (r == 0) ? w3s6[NB] : (r == 1 ? w5s6[NB] : w7s6[NB]); \
        const int K  = (r == 0) ? 3 : (r == 1 ? 5 : 7);                      \
        const int pk = K >> 1;                                               \
        _Pragma("unroll")                                                    \
        for (int oi = 0; oi < 9; ++oi) {                                     \
            const int o = oi - 3;                                            \
            float s = 0.f;                                                   \
            _Pragma("unroll")                                                \
            for (int k = 0; k < 7; ++k) {                                    \
                if (k < K) {                                                 \
                    const int j = o + pk - k;                                \
                    if (j >= 0 && j < 3) s += wk[k];                         \
                }                                                            \
            }                                                                \
            weff[oi] = s;                                                    \
        }                                                                    \
        _Pragma("unroll")                                                    \
        for (int j = 0; j < 29; ++j) {                                       \
            float s = 0.f;                                                   \
            _Pragma("unroll")                                                \
            for (int oi = 0; oi < 9; ++oi) {                                 \
                const int i = j - oi;                                        \
                if (i >= 0 && i < 21) s = fmaf(weff[oi], firs6[NB][i], s);   \
            }                                                                \
            CK[j] = s;                                                       \
        }                                                                    \
    }

// ---------------------------------------------------------------------------
// Fully fused kernel: one block per batch element b, 768 threads.
//  1. stage all 22 x rows into 3-phase LDS planes (once)
//  2. boundary phase: FIR dots + exact special outputs (corr)
//  3. main loop: thread = (nb-pair, 4-output tile); window read once per
//     channel serves both nb of the pair; barrier-free over 22 channels
//  4. hrow + substitution + pooling (hp, gm stay in LDS)
//  5. stage2 inline: gate/top-3, experts+EBN+ReLU+mix -> feats, FC+logsoftmax
// ---------------------------------------------------------------------------
__global__ __launch_bounds__(NTH, 3) void fb_fused(
    const float* __restrict__ x,
    const float* __restrict__ fir,
    const float* __restrict__ w3,
    const float* __restrict__ w5,
    const float* __restrict__ w7,
    const float* __restrict__ bn_g, const float* __restrict__ bn_b,
    const float* __restrict__ bn_m, const float* __restrict__ bn_v,
    const float* __restrict__ sconv_w,
    const float* __restrict__ gate_w, const float* __restrict__ gate_b,
    const float* __restrict__ exp_w,  const float* __restrict__ exp_b,
    const float* __restrict__ ebn_g,  const float* __restrict__ ebn_b,
    const float* __restrict__ ebn_m,  const float* __restrict__ ebn_v,
    const float* __restrict__ fc_w,   const float* __restrict__ fc_b,
    float* __restrict__ feats_out, float* __restrict__ logp_out)
{
    const int b   = blockIdx.x;
    const int tid = threadIdx.x;

    __shared__ float pl[C_][3][PQ_];     // 92.9 KB
    __shared__ float hrow[NB_][1000];    // 24 KB
    __shared__ float firs6[NB_][21];
    __shared__ float w3s6[NB_][3];
    __shared__ float w5s6[NB_][5];
    __shared__ float w7s6[NB_][7];
    __shared__ float sws6[NB_][C_];
    __shared__ float sbn6[NB_][2];
    __shared__ float xbv[NB_][C_][13];   // xb(0..6), xb(994..999) per (nb,c)
    __shared__ float term[NB_][6][C_];
    __shared__ float corr[NB_][6];
    __shared__ float psum[MNB_];         // pooled sums (nb*8+p)
    __shared__ float hpl[MNB_];          // pooled means
    __shared__ float gms[NB_];
    __shared__ float lg[MNB_];
    __shared__ float gsh[E_];
    __shared__ float fsh[FEAT_];
    __shared__ float fpart[NC_][8];
    __shared__ float lo[NC_];

    // ---- issue x loads early: 22 rows * 250 float4 = 5500 ----
    const float* xbase = x + (size_t)b * (C_ * T_);
    float4 g[8];
    #pragma unroll
    for (int k = 0; k < 8; ++k) {
        const int idx = tid + k * NTH;
        if (idx < 5500) {
            const int c = idx / 250, j = idx % 250;
            g[k] = *(const float4*)(xbase + c * T_ + 4 * j);
        }
    }

    // ---- weights to LDS + halo zeroing ----
    if (tid < 126)                      { int nb=tid/21;  firs6[nb][tid%21] = fir[tid]; }
    else if (tid >= 128 && tid < 146)   { int k=tid-128;  w3s6[k/3][k%3] = w3[k]; }
    else if (tid >= 160 && tid < 190)   { int k=tid-160;  w5s6[k/5][k%5] = w5[k]; }
    else if (tid >= 192 && tid < 234)   { int k=tid-192;  w7s6[k/7][k%7] = w7[k]; }
    else if (tid >= 256 && tid < 388)   { int k=tid-256;  sws6[k/C_][k%C_] = sconv_w[k]; }
    else if (tid >= 400 && tid < 406) {
        const int nb = tid - 400;
        float sc = bn_g[nb] * rsqrtf(bn_v[nb] + 1e-5f);
        sbn6[nb][0] = sc * (1.f/3.f);          // folds the /3 of the triple-mean
        sbn6[nb][1] = bn_b[nb] - bn_m[nb] * sc;
    }
    for (int idx = tid; idx < 1254; idx += NTH) {
        const int c = idx / 57, rem = idx % 57;
        const int p = rem / 19, s = rem % 19;
        const int q = (s < 8) ? s : (333 + s);
        pl[c][p][q] = 0.f;
    }
    __syncthreads();

    // ---- deinterleave staged rows into planes ----
    #pragma unroll
    for (int k = 0; k < 8; ++k) {
        const int idx = tid + k * NTH;
        if (idx < 5500) {
            const int c = idx / 250, j = idx % 250;
            int mm = 4 * j + 24;
            int q  = mm / 3, p = mm - 3 * q;
            const float vv[4] = {g[k].x, g[k].y, g[k].z, g[k].w};
            #pragma unroll
            for (int e2 = 0; e2 < 4; ++e2) {
                pl[c][p][q] = vv[e2];
                ++p; if (p == 3) { p = 0; ++q; }
            }
        }
    }
    __syncthreads();

    // ---- phase B: xbv[nb][c][pos] = FIR dot at m ----
    for (int idx = tid; idx < NB_ * C_ * 13; idx += NTH) {     // 1716
        const int nb  = idx / (C_ * 13);
        const int rem = idx % (C_ * 13);
        const int c   = rem / 13, pos = rem % 13;
        const int m   = (pos < 7) ? pos : (987 + pos);         // 0..6, 994..999
        int mm = m + 14;                                       // (m-10)+24
        int q  = mm / 3, p = mm - 3 * q;
        float s = 0.f;
        #pragma unroll
        for (int i = 0; i < 21; ++i) {
            s = fmaf(firs6[nb][i], pl[c][p][q], s);
            ++p; if (p == 3) { p = 0; ++q; }
        }
        xbv[nb][c][pos] = s;
    }
    __syncthreads();

    // ---- phase C: exact special outputs t in {0,332,333,666,667,999} ----
    for (int idx = tid; idx < NB_ * 6 * C_; idx += NTH) {      // 792
        const int nb  = idx / (6 * C_);
        const int rem = idx % (6 * C_);
        const int tix = rem / C_, c = rem % C_;
        const float* X  = xbv[nb][c];   // X[0..6]=xb(0..6), X[7..12]=xb(994..999)
        const float* W3 = w3s6[nb];
        const float* W5 = w5s6[nb];
        const float* W7 = w7s6[nb];
        float s;
        switch (tix) {
        case 0:
            s = W3[1]*X[0]+W3[2]*X[1]
              + W3[0]*X[0]+W3[1]*X[1]+W3[2]*X[2]
              + W3[0]*X[1]+W3[1]*X[2]+W3[2]*X[3];
            break;
        case 1:
            s = W3[0]*X[8]+W3[1]*X[9]+W3[2]*X[10]
              + W3[0]*X[9]+W3[1]*X[10]+W3[2]*X[11]
              + W3[0]*X[10]+W3[1]*X[11]+W3[2]*X[12];
            break;
        case 2:
            s = W3[0]*X[11]+W3[1]*X[12]
              + W5[2]*X[0]+W5[3]*X[1]+W5[4]*X[2]
              + W5[1]*X[0]+W5[2]*X[1]+W5[3]*X[2]+W5[4]*X[3];
            break;
        case 3:
            s = W5[0]*X[9]+W5[1]*X[10]+W5[2]*X[11]+W5[3]*X[12]
              + W5[0]*X[10]+W5[1]*X[11]+W5[2]*X[12]
              + W7[3]*X[0]+W7[4]*X[1]+W7[5]*X[2]+W7[6]*X[3];
            break;
        case 4:
            s = W7[2]*X[0]+W7[3]*X[1]+W7[4]*X[2]+W7[5]*X[3]+W7[6]*X[4]
              + W7[1]*X[0]+W7[2]*X[1]+W7[3]*X[2]+W7[4]*X[3]+W7[5]*X[4]+W7[6]*X[5]
              + W7[0]*X[0]+W7[1]*X[1]+W7[2]*X[2]+W7[3]*X[3]+W7[4]*X[4]+W7[5]*X[5]+W7[6]*X[6];
            break;
        default:
            s = W7[0]*X[7]+W7[1]*X[8]+W7[2]*X[9]+W7[3]*X[10]+W7[4]*X[11]+W7[5]*X[12]
              + W7[0]*X[8]+W7[1]*X[9]+W7[2]*X[10]+W7[3]*X[11]+W7[4]*X[12]
              + W7[0]*X[9]+W7[1]*X[10]+W7[2]*X[11]+W7[3]*X[12];
            break;
        }
        const float v = fmaxf(fmaf(s, sbn6[nb][0], sbn6[nb][1]), 0.f);
        term[nb][tix][c] = v * sws6[nb][c];
    }
    __syncthreads();
    if (tid < 36) {
        const int nb = tid / 6, tix = tid % 6;
        float s = 0.f;
        for (int c = 0; c < C_; ++c) s += term[nb][tix][c];
        corr[nb][tix] = s;
    }

    // ---- main loop: thread = (pair, 4-output tile), 2 nb per thread ----
    const int  pair = tid >> 8;              // 0,1,2
    const int  lt   = tid & 255;
    const bool act  = (lt <= 249);
    const int  r    = (lt <= 82) ? 0 : ((lt <= 166) ? 1 : 2);
    const int  nb0  = 2 * pair, nb1 = nb0 + 1;

    float ckA[29], ckB[29];
    if (act) { BUILD_CK(ckA, nb0) BUILD_CK(ckB, nb1) }

    float aA0 = 0.f, aA1 = 0.f, aA2 = 0.f, aA3 = 0.f;
    float aB0 = 0.f, aB1 = 0.f, aB2 = 0.f, aB3 = 0.f;

    if (act) {
        const float scA = sbn6[nb0][0], biA = sbn6[nb0][1];
        const float scB = sbn6[nb1][0], biB = sbn6[nb1][1];
        #pragma unroll 1
        for (int c = 0; c < C_; ++c) {
            const float (*bw)[PQ_] = pl[c];
            float f0[16], f1[16], f2[16];
            float sa0 = 0.f, sa1 = 0.f, sa2 = 0.f, sa3 = 0.f;
            float sb0 = 0.f, sb1 = 0.f, sb2 = 0.f, sb3 = 0.f;
            if (r == 0) {
                LOADP(f0, 2, 0) LOADP(f1, 0, 4) LOADP(f2, 1, 4)
                TAPS(f0, 3, 0, 10) TAPS(f1, 0, 1, 10) TAPS(f2, 0, 2, 9)
            } else if (r == 1) {
                LOADP(f0, 1, -332) LOADP(f1, 2, -332) LOADP(f2, 0, -332)
                TAPS(f0, 2, 0, 10) TAPS(f1, 2, 1, 10) TAPS(f2, 3, 2, 9)
            } else {
                LOADP(f0, 0, -664) LOADP(f1, 1, -664) LOADP(f2, 2, -664)
                TAPS(f0, 1, 0, 10) TAPS(f1, 1, 1, 10) TAPS(f2, 1, 2, 9)
            }
            const float swA = sws6[nb0][c], swB = sws6[nb1][c];
            aA0 += fmaxf(fmaf(sa0, scA, biA), 0.f) * swA;
            aA1 += fmaxf(fmaf(sa1, scA, biA), 0.f) * swA;
            aA2 += fmaxf(fmaf(sa2, scA, biA), 0.f) * swA;
            aA3 += fmaxf(fmaf(sa3, scA, biA), 0.f) * swA;
            aB0 += fmaxf(fmaf(sb0, scB, biB), 0.f) * swB;
            aB1 += fmaxf(fmaf(sb1, scB, biB), 0.f) * swB;
            aB2 += fmaxf(fmaf(sb2, scB, biB), 0.f) * swB;
            aB3 += fmaxf(fmaf(sb3, scB, biB), 0.f) * swB;
        }
    }

    __syncthreads();
    if (act) {
        *(float4*)&hrow[nb0][4*lt] = make_float4(aA0, aA1, aA2, aA3);
        *(float4*)&hrow[nb1][4*lt] = make_float4(aB0, aB1, aB2, aB3);
    }
    __syncthreads();
    if (tid < 36) {    // substitute exact special outputs
        const int nb = tid / 6, tix = tid % 6;
        const int t = (tix == 0) ? 0 :
                      (tix <= 2) ? (331 + tix) :        // 332, 333
                      (tix <= 4) ? (663 + tix) : 999;   // 666, 667
        hrow[nb][t] = corr[nb][tix];
    }
    __syncthreads();

    // ---- pooling: 48 windows x 8 threads ----
    if (tid < 384) {
        const int w = tid >> 3, j = tid & 7;
        const int nb = w >> 3, p = w & 7;
        float s = 0.f;
        for (int k = j; k < POOL_; k += 8) s += hrow[nb][p*POOL_ + k];
        s += __shfl_down(s, 4, 8);
        s += __shfl_down(s, 2, 8);
        s += __shfl_down(s, 1, 8);
        if (j == 0) { psum[w] = s; hpl[w] = s * (1.f / POOL_); }
    }
    __syncthreads();
    if (tid < NB_) {
        float s = 0.f;
        for (int p = 0; p < TP_; ++p) s += psum[tid*TP_ + p];
        gms[tid] = s * (1.f / T_);
    }
    __syncthreads();

    // ---- stage2: gate logits ----
    if (tid < MNB_) {
        float s = gate_b[tid];
        for (int c = 0; c < NB_; ++c) s += gms[c] * gate_w[tid*NB_ + c];
        lg[tid] = s;
    }
    __syncthreads();
    if (tid == 0) {
        float mx = lg[0];
        for (int i = 1; i < MNB_; ++i) mx = fmaxf(mx, lg[i]);
        for (int i = 0; i < MNB_; ++i) lg[i] = expf(lg[i] - mx);
        int i1 = 0, i2 = -1, i3 = -1;
        float b1 = -1.f, b2 = -1.f, b3 = -1.f;
        for (int i = 0; i < MNB_; ++i) if (lg[i] > b1) { b1 = lg[i]; i1 = i; }
        for (int i = 0; i < MNB_; ++i) if (i != i1 && lg[i] > b2) { b2 = lg[i]; i2 = i; }
        for (int i = 0; i < MNB_; ++i) if (i != i1 && i != i2 && lg[i] > b3) { b3 = lg[i]; i3 = i; }
        const float s3 = lg[i1] + lg[i2] + lg[i3];
        for (int j = 0; j < E_; ++j) gsh[j] = 0.f;
        if (i1 < E_) gsh[i1] = lg[i1] / s3;
        if (i2 < E_) gsh[i2] = lg[i2] / s3;
        if (i3 < E_) gsh[i3] = lg[i3] / s3;
    }
    __syncthreads();

    // ---- experts + EBN + ReLU + gate-mix -> feats ----
    if (tid < FEAT_) {
        const int o = tid >> 3, p = tid & 7;
        float outv = 0.f;
        #pragma unroll
        for (int e = 0; e < E_; ++e) {
            const int eo = e*MNB_ + o;
            float acc = exp_b[eo];
            #pragma unroll
            for (int c = 0; c < NB_; ++c)
                acc += hpl[c*TP_ + p] * exp_w[eo*NB_ + c];
            const float esc = ebn_g[eo] * rsqrtf(ebn_v[eo] + 1e-5f);
            float v = fmaf(acc - ebn_m[eo], esc, ebn_b[eo]);
            v = fmaxf(v, 0.f);
            outv += gsh[e] * v;
        }
        fsh[tid] = outv;
        feats_out[b*FEAT_ + tid] = outv;
    }
    __syncthreads();

    // ---- FC: 9 classes x 8 partials ----
    if (tid < NC_ * 8) {
        const int cls = tid >> 3, part = tid & 7;
        float s = 0.f;
        const float* wr = fc_w + cls*FEAT_ + part*48;
        const float* fr = fsh + part*48;
        for (int i = 0; i < 48; ++i) s = fmaf(fr[i], wr[i], s);
        fpart[cls][part] = s;
    }
    __syncthreads();
    if (tid < NC_) {
        float s = fc_b[tid];
        for (int p = 0; p < 8; ++p) s += fpart[tid][p];
        lo[tid] = s;
    }
    __syncthreads();
    if (tid == 0) {
        float mx = lo[0];
        for (int k = 1; k < NC_; ++k) mx = fmaxf(mx, lo[k]);
        float Z = 0.f;
        for (int k = 0; k < NC_; ++k) Z += expf(lo[k] - mx);
        const float lse = mx + logf(Z);
        for (int k = 0; k < NC_; ++k) logp_out[b*NC_ + k] = lo[k] - lse;
    }
}

extern "C" void kernel_launch(void* const* d_in, const int* in_sizes, int n_in,
                              void* d_out, int out_size, void* d_ws, size_t ws_size,
                              hipStream_t stream) {
    const float* x       = (const float*)d_in[0];
    const float* fir     = (const float*)d_in[1];
    const float* w3      = (const float*)d_in[2];
    const float* w5      = (const float*)d_in[3];
    const float* w7      = (const float*)d_in[4];
    const float* bn1_g   = (const float*)d_in[5];
    const float* bn1_b   = (const float*)d_in[6];
    const float* bn1_m   = (const float*)d_in[7];
    const float* bn1_v   = (const float*)d_in[8];
    const float* sconv_w = (const float*)d_in[9];
    const float* gate_w  = (const float*)d_in[10];
    const float* gate_b  = (const float*)d_in[11];
    const float* exp_w   = (const float*)d_in[12];
    const float* exp_b   = (const float*)d_in[13];
    const float* ebn_g   = (const float*)d_in[14];
    const float* ebn_b   = (const float*)d_in[15];
    const float* ebn_m   = (const float*)d_in[16];
    const float* ebn_v   = (const float*)d_in[17];
    const float* fc_w    = (const float*)d_in[18];
    const float* fc_b    = (const float*)d_in[19];

    float* out       = (float*)d_out;
    float* feats_out = out;                     // (256, 384)
    float* logp_out  = out + B_ * FEAT_;        // (256, 9)

    fb_fused<<<B_, NTH, 0, stream>>>(x, fir, w3, w5, w7,
                                     bn1_g, bn1_b, bn1_m, bn1_v, sconv_w,
                                     gate_w, gate_b, exp_w, exp_b,
                                     ebn_g, ebn_b, ebn_m, ebn_v,
                                     fc_w, fc_b, feats_out, logp_out);
}

// Round 7
// 56.445 us; speedup vs baseline: 4.3041x; 1.3540x over previous
//
#include <hip/hip_runtime.h>
#include <math.h>

#define B_    256
#define C_    22
#define T_    1000
#define NB_   6
#define E_    6
#define MNB_  48
#define POOL_ 125
#define TP_   8
#define NC_   9
#define FEAT_ 384   // MNB_*TP_

#define PQ_   352    // plane length; x[m] lives at (plane (m+24)%3, q (m+24)/3)
#define NTH   768

// Load 4 aligned float4 (16 floats) from plane pp at element base 4*tile+Aoff.
#define LOADP(F, pp, Aoff)                                                   \
    {                                                                        \
        const float4* pb = (const float4*)&bw[pp][4*tile + (Aoff)];          \
        float4 q0 = pb[0], q1 = pb[1], q2 = pb[2], q3 = pb[3];               \
        *(float4*)&F[0]  = q0; *(float4*)&F[4]  = q1;                        \
        *(float4*)&F[8]  = q2; *(float4*)&F[12] = q3;                        \
    }

// Apply taps of BOTH nb of the pair to window F.
#define TAPS(F, idx0, j0, nj)                                                \
    _Pragma("unroll")                                                        \
    for (int a = 0; a < (nj); ++a) {                                         \
        const float ca = ckA[(j0) + 3*a];                                    \
        const float cb = ckB[(j0) + 3*a];                                    \
        sa0 = fmaf(ca, F[(idx0) + a    ], sa0);                              \
        sa1 = fmaf(ca, F[(idx0) + a + 1], sa1);                              \
        sa2 = fmaf(ca, F[(idx0) + a + 2], sa2);                              \
        sa3 = fmaf(ca, F[(idx0) + a + 3], sa3);                              \
        sb0 = fmaf(cb, F[(idx0) + a    ], sb0);                              \
        sb1 = fmaf(cb, F[(idx0) + a + 1], sb1);                              \
        sb2 = fmaf(cb, F[(idx0) + a + 2], sb2);                              \
        sb3 = fmaf(cb, F[(idx0) + a + 3], sb3);                              \
    }

// ---------------------------------------------------------------------------
// Fully fused kernel: one block per batch element b, 768 threads.
//  - stage x into 3-phase planes via stride-3 loads + immediate b128 writes
//    (no reg-resident tile -> no spill; halos folded into the same loop)
//  - ckl[3][6][29] fused-tap table built once in LDS
//  - main loop: wave-uniform region (4 waves per r), thread = (pair, tile),
//    per-thread ckA/ckB gathered from ckl -> no divergent double-path
// ---------------------------------------------------------------------------
__global__ __launch_bounds__(NTH, 3) void fb_fused(
    const float* __restrict__ x,
    const float* __restrict__ fir,
    const float* __restrict__ w3,
    const float* __restrict__ w5,
    const float* __restrict__ w7,
    const float* __restrict__ bn_g, const float* __restrict__ bn_b,
    const float* __restrict__ bn_m, const float* __restrict__ bn_v,
    const float* __restrict__ sconv_w,
    const float* __restrict__ gate_w, const float* __restrict__ gate_b,
    const float* __restrict__ exp_w,  const float* __restrict__ exp_b,
    const float* __restrict__ ebn_g,  const float* __restrict__ ebn_b,
    const float* __restrict__ ebn_m,  const float* __restrict__ ebn_v,
    const float* __restrict__ fc_w,   const float* __restrict__ fc_b,
    float* __restrict__ feats_out, float* __restrict__ logp_out)
{
    const int b   = blockIdx.x;
    const int tid = threadIdx.x;

    __shared__ __align__(16) float pl[C_][3][PQ_];   // 92.9 KB
    __shared__ __align__(16) float hrow[NB_][1000];  // 24 KB
    __shared__ float firs6[NB_][21];
    __shared__ float w3s6[NB_][3];
    __shared__ float w5s6[NB_][5];
    __shared__ float w7s6[NB_][7];
    __shared__ float sws6[NB_][C_];
    __shared__ float sbn6[NB_][2];
    __shared__ float ckl[3][NB_][29];    // fused 29-tap kernels per (r, nb)
    __shared__ float xbv[NB_][C_][13];   // xb(0..6), xb(994..999) per (nb,c)
    __shared__ float term[NB_][6][C_];
    __shared__ float corr[NB_][6];
    __shared__ float psum[MNB_];
    __shared__ float hpl[MNB_];
    __shared__ float gms[NB_];
    __shared__ float lg[MNB_];
    __shared__ float gsh[E_];
    __shared__ float fsh[FEAT_];
    __shared__ float fpart[NC_][8];
    __shared__ float lo[NC_];

    const float* xbase = x + (size_t)b * (C_ * T_);

    // ---- weights to LDS ----
    if (tid < 126)                      { int nb=tid/21;  firs6[nb][tid%21] = fir[tid]; }
    else if (tid >= 128 && tid < 146)   { int k=tid-128;  w3s6[k/3][k%3] = w3[k]; }
    else if (tid >= 160 && tid < 190)   { int k=tid-160;  w5s6[k/5][k%5] = w5[k]; }
    else if (tid >= 192 && tid < 234)   { int k=tid-192;  w7s6[k/7][k%7] = w7[k]; }
    else if (tid >= 256 && tid < 388)   { int k=tid-256;  sws6[k/C_][k%C_] = sconv_w[k]; }
    else if (tid >= 400 && tid < 406) {
        const int nb = tid - 400;
        float sc = bn_g[nb] * rsqrtf(bn_v[nb] + 1e-5f);
        sbn6[nb][0] = sc * (1.f/3.f);          // folds the /3 of the triple-mean
        sbn6[nb][1] = bn_b[nb] - bn_m[nb] * sc;
    }

    // ---- stage x directly in plane order: item = (c, p, 4-q tile) ----
    // per (c,p): 88 tiles cover phys q 0..351 (halos zeroed by the guard)
    #pragma unroll
    for (int k = 0; k < 8; ++k) {
        const int idx = tid + k * NTH;            // 0..5807
        if (idx < 5808) {
            const int c   = idx / 264;
            const int rem = idx % 264;
            const int p   = rem / 88;
            const int q0  = (rem % 88) * 4;
            const float* xr = xbase + c * T_;
            float v[4];
            #pragma unroll
            for (int i = 0; i < 4; ++i) {
                const int m  = 3 * (q0 + i) + p - 24;
                const int mc = m < 0 ? 0 : (m > 999 ? 999 : m);
                const float val = xr[mc];
                v[i] = ((unsigned)m < 1000u) ? val : 0.f;
            }
            *(float4*)&pl[c][p][q0] = make_float4(v[0], v[1], v[2], v[3]);
        }
    }
    __syncthreads();

    // ---- build ckl (needs weights) ∥ phase B: xbv FIR dots (needs pl) ----
    {
        const int idx = tid;                      // 522 = 18 combos * 29 taps
        if (idx < 522) {
            const int combo = idx / 29, jj = idx % 29;
            const int rr = combo / 6, nb = combo % 6;
            const float* wk = (rr == 0) ? w3s6[nb] : (rr == 1 ? w5s6[nb] : w7s6[nb]);
            const int K  = (rr == 0) ? 3 : (rr == 1 ? 5 : 7);
            const int pk = K >> 1;
            float s = 0.f;
            #pragma unroll
            for (int oi = 0; oi < 9; ++oi) {
                const int o = oi - 3;
                float we = 0.f;
                for (int k = 0; k < 7; ++k) {
                    if (k < K) {
                        const int jx = o + pk - k;
                        if (jx >= 0 && jx < 3) we += wk[k];
                    }
                }
                const int i = jj - oi;
                if (i >= 0 && i < 21) s = fmaf(we, firs6[nb][i], s);
            }
            ckl[rr][nb][jj] = s;
        }
    }
    for (int idx = tid; idx < NB_ * C_ * 13; idx += NTH) {     // 1716
        const int nb  = idx / (C_ * 13);
        const int rem = idx % (C_ * 13);
        const int c   = rem / 13, pos = rem % 13;
        const int m   = (pos < 7) ? pos : (987 + pos);         // 0..6, 994..999
        int mm = m + 14;                                       // (m-10)+24
        int q  = mm / 3, p = mm - 3 * q;
        float s = 0.f;
        #pragma unroll
        for (int i = 0; i < 21; ++i) {
            s = fmaf(firs6[nb][i], pl[c][p][q], s);
            ++p; if (p == 3) { p = 0; ++q; }
        }
        xbv[nb][c][pos] = s;
    }
    __syncthreads();

    // ---- phase C: exact special outputs t in {0,332,333,666,667,999} ----
    for (int idx = tid; idx < NB_ * 6 * C_; idx += NTH) {      // 792
        const int nb  = idx / (6 * C_);
        const int rem = idx % (6 * C_);
        const int tix = rem / C_, c = rem % C_;
        const float* X  = xbv[nb][c];   // X[0..6]=xb(0..6), X[7..12]=xb(994..999)
        const float* W3 = w3s6[nb];
        const float* W5 = w5s6[nb];
        const float* W7 = w7s6[nb];
        float s;
        switch (tix) {
        case 0:
            s = W3[1]*X[0]+W3[2]*X[1]
              + W3[0]*X[0]+W3[1]*X[1]+W3[2]*X[2]
              + W3[0]*X[1]+W3[1]*X[2]+W3[2]*X[3];
            break;
        case 1:
            s = W3[0]*X[8]+W3[1]*X[9]+W3[2]*X[10]
              + W3[0]*X[9]+W3[1]*X[10]+W3[2]*X[11]
              + W3[0]*X[10]+W3[1]*X[11]+W3[2]*X[12];
            break;
        case 2:
            s = W3[0]*X[11]+W3[1]*X[12]
              + W5[2]*X[0]+W5[3]*X[1]+W5[4]*X[2]
              + W5[1]*X[0]+W5[2]*X[1]+W5[3]*X[2]+W5[4]*X[3];
            break;
        case 3:
            s = W5[0]*X[9]+W5[1]*X[10]+W5[2]*X[11]+W5[3]*X[12]
              + W5[0]*X[10]+W5[1]*X[11]+W5[2]*X[12]
              + W7[3]*X[0]+W7[4]*X[1]+W7[5]*X[2]+W7[6]*X[3];
            break;
        case 4:
            s = W7[2]*X[0]+W7[3]*X[1]+W7[4]*X[2]+W7[5]*X[3]+W7[6]*X[4]
              + W7[1]*X[0]+W7[2]*X[1]+W7[3]*X[2]+W7[4]*X[3]+W7[5]*X[4]+W7[6]*X[5]
              + W7[0]*X[0]+W7[1]*X[1]+W7[2]*X[2]+W7[3]*X[3]+W7[4]*X[4]+W7[5]*X[5]+W7[6]*X[6];
            break;
        default:
            s = W7[0]*X[7]+W7[1]*X[8]+W7[2]*X[9]+W7[3]*X[10]+W7[4]*X[11]+W7[5]*X[12]
              + W7[0]*X[8]+W7[1]*X[9]+W7[2]*X[10]+W7[3]*X[11]+W7[4]*X[12]
              + W7[0]*X[9]+W7[1]*X[10]+W7[2]*X[11]+W7[3]*X[12];
            break;
        }
        const float v = fmaxf(fmaf(s, sbn6[nb][0], sbn6[nb][1]), 0.f);
        term[nb][tix][c] = v * sws6[nb][c];
    }

    // ---- wave-uniform region decomposition ----
    const int rr = tid >> 8;                 // region 0,1,2 — uniform per wave
    const int j  = tid & 255;
    int pair = 0, tile = 0;
    bool act = false;
    if (rr == 0)      { act = (j < 249); pair = j / 83; tile = j % 83; }
    else if (rr == 1) { act = (j < 252); pair = j / 84; tile = 83 + j % 84; }
    else              { act = (j < 249); pair = j / 83; tile = 167 + j % 83; }
    const int nb0 = 2 * pair, nb1 = nb0 + 1;

    // gather per-thread fused taps + BN constants (runtime rr/nb, unrolled idx)
    float ckA[29], ckB[29];
    float scA = 0.f, biA = 0.f, scB = 0.f, biB = 0.f;
    __syncthreads();          // term + ckl visible
    if (act) {
        #pragma unroll
        for (int t2 = 0; t2 < 29; ++t2) {
            ckA[t2] = ckl[rr][nb0][t2];
            ckB[t2] = ckl[rr][nb1][t2];
        }
        scA = sbn6[nb0][0]; biA = sbn6[nb0][1];
        scB = sbn6[nb1][0]; biB = sbn6[nb1][1];
    }
    if (tid < 36) {           // corr reduce (read after next barrier)
        const int nb = tid / 6, tix = tid % 6;
        float s = 0.f;
        for (int c = 0; c < C_; ++c) s += term[nb][tix][c];
        corr[nb][tix] = s;
    }

    // ---- main loop: barrier-free, wave-uniform path ----
    float aA0 = 0.f, aA1 = 0.f, aA2 = 0.f, aA3 = 0.f;
    float aB0 = 0.f, aB1 = 0.f, aB2 = 0.f, aB3 = 0.f;
    if (act) {
        #pragma unroll 1
        for (int c = 0; c < C_; ++c) {
            const float (*bw)[PQ_] = pl[c];
            float f0[16], f1[16], f2[16];
            float sa0 = 0.f, sa1 = 0.f, sa2 = 0.f, sa3 = 0.f;
            float sb0 = 0.f, sb1 = 0.f, sb2 = 0.f, sb3 = 0.f;
            if (rr == 0) {
                LOADP(f0, 2, 0) LOADP(f1, 0, 4) LOADP(f2, 1, 4)
                TAPS(f0, 3, 0, 10) TAPS(f1, 0, 1, 10) TAPS(f2, 0, 2, 9)
            } else if (rr == 1) {
                LOADP(f0, 1, -332) LOADP(f1, 2, -332) LOADP(f2, 0, -332)
                TAPS(f0, 2, 0, 10) TAPS(f1, 2, 1, 10) TAPS(f2, 3, 2, 9)
            } else {
                LOADP(f0, 0, -664) LOADP(f1, 1, -664) LOADP(f2, 2, -664)
                TAPS(f0, 1, 0, 10) TAPS(f1, 1, 1, 10) TAPS(f2, 1, 2, 9)
            }
            const float swA = sws6[nb0][c], swB = sws6[nb1][c];
            aA0 += fmaxf(fmaf(sa0, scA, biA), 0.f) * swA;
            aA1 += fmaxf(fmaf(sa1, scA, biA), 0.f) * swA;
            aA2 += fmaxf(fmaf(sa2, scA, biA), 0.f) * swA;
            aA3 += fmaxf(fmaf(sa3, scA, biA), 0.f) * swA;
            aB0 += fmaxf(fmaf(sb0, scB, biB), 0.f) * swB;
            aB1 += fmaxf(fmaf(sb1, scB, biB), 0.f) * swB;
            aB2 += fmaxf(fmaf(sb2, scB, biB), 0.f) * swB;
            aB3 += fmaxf(fmaf(sb3, scB, biB), 0.f) * swB;
        }
        *(float4*)&hrow[nb0][4*tile] = make_float4(aA0, aA1, aA2, aA3);
        *(float4*)&hrow[nb1][4*tile] = make_float4(aB0, aB1, aB2, aB3);
    }
    __syncthreads();
    if (tid < 36) {    // substitute exact special outputs
        const int nb = tid / 6, tix = tid % 6;
        const int t = (tix == 0) ? 0 :
                      (tix <= 2) ? (331 + tix) :        // 332, 333
                      (tix <= 4) ? (663 + tix) : 999;   // 666, 667
        hrow[nb][t] = corr[nb][tix];
    }
    __syncthreads();

    // ---- pooling: 48 windows x 8 threads ----
    if (tid < 384) {
        const int w = tid >> 3, jj = tid & 7;
        const int nb = w >> 3, p = w & 7;
        float s = 0.f;
        for (int k = jj; k < POOL_; k += 8) s += hrow[nb][p*POOL_ + k];
        s += __shfl_down(s, 4, 8);
        s += __shfl_down(s, 2, 8);
        s += __shfl_down(s, 1, 8);
        if (jj == 0) { psum[w] = s; hpl[w] = s * (1.f / POOL_); }
    }
    __syncthreads();
    if (tid < NB_) {
        float s = 0.f;
        for (int p = 0; p < TP_; ++p) s += psum[tid*TP_ + p];
        gms[tid] = s * (1.f / T_);
    }
    __syncthreads();

    // ---- stage2: gate logits ----
    if (tid < MNB_) {
        float s = gate_b[tid];
        for (int c = 0; c < NB_; ++c) s += gms[c] * gate_w[tid*NB_ + c];
        lg[tid] = s;
    }
    __syncthreads();
    if (tid == 0) {
        float mx = lg[0];
        for (int i = 1; i < MNB_; ++i) mx = fmaxf(mx, lg[i]);
        for (int i = 0; i < MNB_; ++i) lg[i] = expf(lg[i] - mx);
        int i1 = 0, i2 = -1, i3 = -1;
        float b1 = -1.f, b2 = -1.f, b3 = -1.f;
        for (int i = 0; i < MNB_; ++i) if (lg[i] > b1) { b1 = lg[i]; i1 = i; }
        for (int i = 0; i < MNB_; ++i) if (i != i1 && lg[i] > b2) { b2 = lg[i]; i2 = i; }
        for (int i = 0; i < MNB_; ++i) if (i != i1 && i != i2 && lg[i] > b3) { b3 = lg[i]; i3 = i; }
        const float s3 = lg[i1] + lg[i2] + lg[i3];
        for (int jj = 0; jj < E_; ++jj) gsh[jj] = 0.f;
        if (i1 < E_) gsh[i1] = lg[i1] / s3;
        if (i2 < E_) gsh[i2] = lg[i2] / s3;
        if (i3 < E_) gsh[i3] = lg[i3] / s3;
    }
    __syncthreads();

    // ---- experts + EBN + ReLU + gate-mix -> feats ----
    if (tid < FEAT_) {
        const int o = tid >> 3, p = tid & 7;
        float outv = 0.f;
        #pragma unroll
        for (int e = 0; e < E_; ++e) {
            const int eo = e*MNB_ + o;
            float acc = exp_b[eo];
            #pragma unroll
            for (int c = 0; c < NB_; ++c)
                acc += hpl[c*TP_ + p] * exp_w[eo*NB_ + c];
            const float esc = ebn_g[eo] * rsqrtf(ebn_v[eo] + 1e-5f);
            float v = fmaf(acc - ebn_m[eo], esc, ebn_b[eo]);
            v = fmaxf(v, 0.f);
            outv += gsh[e] * v;
        }
        fsh[tid] = outv;
        feats_out[b*FEAT_ + tid] = outv;
    }
    __syncthreads();

    // ---- FC: 9 classes x 8 partials ----
    if (tid < NC_ * 8) {
        const int cls = tid >> 3, part = tid & 7;
        float s = 0.f;
        const float* wr = fc_w + cls*FEAT_ + part*48;
        const float* fr = fsh + part*48;
        for (int i = 0; i < 48; ++i) s = fmaf(fr[i], wr[i], s);
        fpart[cls][part] = s;
    }
    __syncthreads();
    if (tid < NC_) {
        float s = fc_b[tid];
        for (int p = 0; p < 8; ++p) s += fpart[tid][p];
        lo[tid] = s;
    }
    __syncthreads();
    if (tid == 0) {
        float mx = lo[0];
        for (int k = 1; k < NC_; ++k) mx = fmaxf(mx, lo[k]);
        float Z = 0.f;
        for (int k = 0; k < NC_; ++k) Z += expf(lo[k] - mx);
        const float lse = mx + logf(Z);
        for (int k = 0; k < NC_; ++k) logp_out[b*NC_ + k] = lo[k] - lse;
    }
}

extern "C" void kernel_launch(void* const* d_in, const int* in_sizes, int n_in,
                              void* d_out, int out_size, void* d_ws, size_t ws_size,
                              hipStream_t stream) {
    const float* x       = (const float*)d_in[0];
    const float* fir     = (const float*)d_in[1];
    const float* w3      = (const float*)d_in[2];
    const float* w5      = (const float*)d_in[3];
    const float* w7      = (const float*)d_in[4];
    const float* bn1_g   = (const float*)d_in[5];
    const float* bn1_b   = (const float*)d_in[6];
    const float* bn1_m   = (const float*)d_in[7];
    const float* bn1_v   = (const float*)d_in[8];
    const float* sconv_w = (const float*)d_in[9];
    const float* gate_w  = (const float*)d_in[10];
    const float* gate_b  = (const float*)d_in[11];
    const float* exp_w   = (const float*)d_in[12];
    const float* exp_b   = (const float*)d_in[13];
    const float* ebn_g   = (const float*)d_in[14];
    const float* ebn_b   = (const float*)d_in[15];
    const float* ebn_m   = (const float*)d_in[16];
    const float* ebn_v   = (const float*)d_in[17];
    const float* fc_w    = (const float*)d_in[18];
    const float* fc_b    = (const float*)d_in[19];

    float* out       = (float*)d_out;
    float* feats_out = out;                     // (256, 384)
    float* logp_out  = out + B_ * FEAT_;        // (256, 9)

    fb_fused<<<B_, NTH, 0, stream>>>(x, fir, w3, w5, w7,
                                     bn1_g, bn1_b, bn1_m, bn1_v, sconv_w,
                                     gate_w, gate_b, exp_w, exp_b,
                                     ebn_g, ebn_b, ebn_m, ebn_v,
                                     fc_w, fc_b, feats_out, logp_out);
}

// Round 8
// 55.781 us; speedup vs baseline: 4.3554x; 1.0119x over previous
//
#include <hip/hip_runtime.h>
#include <math.h>

#define B_    256
#define C_    22
#define T_    1000
#define NB_   6
#define E_    6
#define MNB_  48
#define POOL_ 125
#define TP_   8
#define NC_   9
#define FEAT_ 384   // MNB_*TP_

#define PQ_   352    // plane length; x[m] lives at (plane (m+24)%3, q (m+24)/3)
#define NTH   768

// Load 4 aligned float4 (16 floats) from plane pp at element base 4*tile+Aoff.
#define LOADP(F, pp, Aoff)                                                   \
    {                                                                        \
        const float4* pb = (const float4*)&bw[pp][4*tile + (Aoff)];          \
        float4 q0 = pb[0], q1 = pb[1], q2 = pb[2], q3 = pb[3];               \
        *(float4*)&F[0]  = q0; *(float4*)&F[4]  = q1;                        \
        *(float4*)&F[8]  = q2; *(float4*)&F[12] = q3;                        \
    }

// Apply taps of BOTH nb of the pair to window F.
#define TAPS(F, idx0, j0, nj)                                                \
    _Pragma("unroll")                                                        \
    for (int a = 0; a < (nj); ++a) {                                         \
        const float ca = ckA[(j0) + 3*a];                                    \
        const float cb = ckB[(j0) + 3*a];                                    \
        sa0 = fmaf(ca, F[(idx0) + a    ], sa0);                              \
        sa1 = fmaf(ca, F[(idx0) + a + 1], sa1);                              \
        sa2 = fmaf(ca, F[(idx0) + a + 2], sa2);                              \
        sa3 = fmaf(ca, F[(idx0) + a + 3], sa3);                              \
        sb0 = fmaf(cb, F[(idx0) + a    ], sb0);                              \
        sb1 = fmaf(cb, F[(idx0) + a + 1], sb1);                              \
        sb2 = fmaf(cb, F[(idx0) + a + 2], sb2);                              \
        sb3 = fmaf(cb, F[(idx0) + a + 3], sb3);                              \
    }

// ---------------------------------------------------------------------------
// Fully fused kernel: one block per batch element b, 768 threads.
// LDS (130 KB) caps the CU at 1 block = 12 waves = EXACTLY 3 waves/SIMD, so
// pin waves_per_eu(3,3): lets regalloc use ~170 VGPRs instead of spilling
// (R7: VGPR=84 + 6.5 MB scratch WRITE per dispatch).
// ---------------------------------------------------------------------------
__global__ __attribute__((amdgpu_waves_per_eu(3, 3)))
__launch_bounds__(NTH) void fb_fused(
    const float* __restrict__ x,
    const float* __restrict__ fir,
    const float* __restrict__ w3,
    const float* __restrict__ w5,
    const float* __restrict__ w7,
    const float* __restrict__ bn_g, const float* __restrict__ bn_b,
    const float* __restrict__ bn_m, const float* __restrict__ bn_v,
    const float* __restrict__ sconv_w,
    const float* __restrict__ gate_w, const float* __restrict__ gate_b,
    const float* __restrict__ exp_w,  const float* __restrict__ exp_b,
    const float* __restrict__ ebn_g,  const float* __restrict__ ebn_b,
    const float* __restrict__ ebn_m,  const float* __restrict__ ebn_v,
    const float* __restrict__ fc_w,   const float* __restrict__ fc_b,
    float* __restrict__ feats_out, float* __restrict__ logp_out)
{
    const int b   = blockIdx.x;
    const int tid = threadIdx.x;

    __shared__ __align__(16) float pl[C_][3][PQ_];   // 92.9 KB
    __shared__ __align__(16) float hrow[NB_][1000];  // 24 KB
    __shared__ float firs6[NB_][21];
    __shared__ float w3s6[NB_][3];
    __shared__ float w5s6[NB_][5];
    __shared__ float w7s6[NB_][7];
    __shared__ float sws6[NB_][C_];
    __shared__ float sbn6[NB_][2];
    __shared__ float ckl[3][NB_][29];    // fused 29-tap kernels per (r, nb)
    __shared__ float xbv[NB_][C_][13];   // xb(0..6), xb(994..999) per (nb,c)
    __shared__ float term[NB_][6][C_];
    __shared__ float corr[NB_][6];
    __shared__ float psum[MNB_];
    __shared__ float hpl[MNB_];
    __shared__ float gms[NB_];
    __shared__ float lg[MNB_];
    __shared__ float gsh[E_];
    __shared__ float fsh[FEAT_];
    __shared__ float fpart[NC_][8];
    __shared__ float lo[NC_];

    const float* xbase = x + (size_t)b * (C_ * T_);

    // ---- weights to LDS ----
    if (tid < 126)                      { int nb=tid/21;  firs6[nb][tid%21] = fir[tid]; }
    else if (tid >= 128 && tid < 146)   { int k=tid-128;  w3s6[k/3][k%3] = w3[k]; }
    else if (tid >= 160 && tid < 190)   { int k=tid-160;  w5s6[k/5][k%5] = w5[k]; }
    else if (tid >= 192 && tid < 234)   { int k=tid-192;  w7s6[k/7][k%7] = w7[k]; }
    else if (tid >= 256 && tid < 388)   { int k=tid-256;  sws6[k/C_][k%C_] = sconv_w[k]; }
    else if (tid >= 400 && tid < 406) {
        const int nb = tid - 400;
        float sc = bn_g[nb] * rsqrtf(bn_v[nb] + 1e-5f);
        sbn6[nb][0] = sc * (1.f/3.f);          // folds the /3 of the triple-mean
        sbn6[nb][1] = bn_b[nb] - bn_m[nb] * sc;
    }

    // ---- stage x directly in plane order: item = (c, p, 4-q tile) ----
    #pragma unroll
    for (int k = 0; k < 8; ++k) {
        const int idx = tid + k * NTH;            // 0..5807
        if (idx < 5808) {
            const int c   = idx / 264;
            const int rem = idx % 264;
            const int p   = rem / 88;
            const int q0  = (rem % 88) * 4;
            const float* xr = xbase + c * T_;
            float v[4];
            #pragma unroll
            for (int i = 0; i < 4; ++i) {
                const int m  = 3 * (q0 + i) + p - 24;
                const int mc = m < 0 ? 0 : (m > 999 ? 999 : m);
                const float val = xr[mc];
                v[i] = ((unsigned)m < 1000u) ? val : 0.f;
            }
            *(float4*)&pl[c][p][q0] = make_float4(v[0], v[1], v[2], v[3]);
        }
    }
    __syncthreads();

    // ---- build ckl (needs weights) ∥ phase B: xbv FIR dots (needs pl) ----
    {
        const int idx = tid;                      // 522 = 18 combos * 29 taps
        if (idx < 522) {
            const int combo = idx / 29, jj = idx % 29;
            const int rr2 = combo / 6, nb = combo % 6;
            const float* wk = (rr2 == 0) ? w3s6[nb] : (rr2 == 1 ? w5s6[nb] : w7s6[nb]);
            const int K  = (rr2 == 0) ? 3 : (rr2 == 1 ? 5 : 7);
            const int pk = K >> 1;
            float s = 0.f;
            #pragma unroll
            for (int oi = 0; oi < 9; ++oi) {
                const int o = oi - 3;
                float we = 0.f;
                for (int k = 0; k < 7; ++k) {
                    if (k < K) {
                        const int jx = o + pk - k;
                        if (jx >= 0 && jx < 3) we += wk[k];
                    }
                }
                const int i = jj - oi;
                if (i >= 0 && i < 21) s = fmaf(we, firs6[nb][i], s);
            }
            ckl[rr2][nb][jj] = s;
        }
    }
    for (int idx = tid; idx < NB_ * C_ * 13; idx += NTH) {     // 1716
        const int nb  = idx / (C_ * 13);
        const int rem = idx % (C_ * 13);
        const int c   = rem / 13, pos = rem % 13;
        const int m   = (pos < 7) ? pos : (987 + pos);         // 0..6, 994..999
        int mm = m + 14;                                       // (m-10)+24
        int q  = mm / 3, p = mm - 3 * q;
        float s = 0.f;
        #pragma unroll
        for (int i = 0; i < 21; ++i) {
            s = fmaf(firs6[nb][i], pl[c][p][q], s);
            ++p; if (p == 3) { p = 0; ++q; }
        }
        xbv[nb][c][pos] = s;
    }
    __syncthreads();

    // ---- phase C: exact special outputs t in {0,332,333,666,667,999} ----
    for (int idx = tid; idx < NB_ * 6 * C_; idx += NTH) {      // 792
        const int nb  = idx / (6 * C_);
        const int rem = idx % (6 * C_);
        const int tix = rem / C_, c = rem % C_;
        const float* X  = xbv[nb][c];   // X[0..6]=xb(0..6), X[7..12]=xb(994..999)
        const float* W3 = w3s6[nb];
        const float* W5 = w5s6[nb];
        const float* W7 = w7s6[nb];
        float s;
        switch (tix) {
        case 0:
            s = W3[1]*X[0]+W3[2]*X[1]
              + W3[0]*X[0]+W3[1]*X[1]+W3[2]*X[2]
              + W3[0]*X[1]+W3[1]*X[2]+W3[2]*X[3];
            break;
        case 1:
            s = W3[0]*X[8]+W3[1]*X[9]+W3[2]*X[10]
              + W3[0]*X[9]+W3[1]*X[10]+W3[2]*X[11]
              + W3[0]*X[10]+W3[1]*X[11]+W3[2]*X[12];
            break;
        case 2:
            s = W3[0]*X[11]+W3[1]*X[12]
              + W5[2]*X[0]+W5[3]*X[1]+W5[4]*X[2]
              + W5[1]*X[0]+W5[2]*X[1]+W5[3]*X[2]+W5[4]*X[3];
            break;
        case 3:
            s = W5[0]*X[9]+W5[1]*X[10]+W5[2]*X[11]+W5[3]*X[12]
              + W5[0]*X[10]+W5[1]*X[11]+W5[2]*X[12]
              + W7[3]*X[0]+W7[4]*X[1]+W7[5]*X[2]+W7[6]*X[3];
            break;
        case 4:
            s = W7[2]*X[0]+W7[3]*X[1]+W7[4]*X[2]+W7[5]*X[3]+W7[6]*X[4]
              + W7[1]*X[0]+W7[2]*X[1]+W7[3]*X[2]+W7[4]*X[3]+W7[5]*X[4]+W7[6]*X[5]
              + W7[0]*X[0]+W7[1]*X[1]+W7[2]*X[2]+W7[3]*X[3]+W7[4]*X[4]+W7[5]*X[5]+W7[6]*X[6];
            break;
        default:
            s = W7[0]*X[7]+W7[1]*X[8]+W7[2]*X[9]+W7[3]*X[10]+W7[4]*X[11]+W7[5]*X[12]
              + W7[0]*X[8]+W7[1]*X[9]+W7[2]*X[10]+W7[3]*X[11]+W7[4]*X[12]
              + W7[0]*X[9]+W7[1]*X[10]+W7[2]*X[11]+W7[3]*X[12];
            break;
        }
        const float v = fmaxf(fmaf(s, sbn6[nb][0], sbn6[nb][1]), 0.f);
        term[nb][tix][c] = v * sws6[nb][c];
    }
    __syncthreads();          // term + ckl visible

    if (tid < 36) {           // corr reduce FIRST (shortens ck live range)
        const int nb = tid / 6, tix = tid % 6;
        float s = 0.f;
        for (int c = 0; c < C_; ++c) s += term[nb][tix][c];
        corr[nb][tix] = s;
    }

    // ---- wave-uniform region decomposition ----
    const int rr = tid >> 8;                 // region 0,1,2 — uniform per wave
    const int j  = tid & 255;
    int pair = 0, tile = 0;
    bool act = false;
    if (rr == 0)      { act = (j < 249); pair = j / 83; tile = j % 83; }
    else if (rr == 1) { act = (j < 252); pair = j / 84; tile = 83 + j % 84; }
    else              { act = (j < 249); pair = j / 83; tile = 167 + j % 83; }
    const int nb0 = 2 * pair, nb1 = nb0 + 1;

    // gather per-thread fused taps + BN constants
    float ckA[29], ckB[29];
    float scA = 0.f, biA = 0.f, scB = 0.f, biB = 0.f;
    if (act) {
        #pragma unroll
        for (int t2 = 0; t2 < 29; ++t2) {
            ckA[t2] = ckl[rr][nb0][t2];
            ckB[t2] = ckl[rr][nb1][t2];
        }
        scA = sbn6[nb0][0]; biA = sbn6[nb0][1];
        scB = sbn6[nb1][0]; biB = sbn6[nb1][1];
    }

    // ---- main loop: barrier-free, wave-uniform path ----
    if (act) {
        float aA0 = 0.f, aA1 = 0.f, aA2 = 0.f, aA3 = 0.f;
        float aB0 = 0.f, aB1 = 0.f, aB2 = 0.f, aB3 = 0.f;
        #pragma unroll 1
        for (int c = 0; c < C_; ++c) {
            const float (*bw)[PQ_] = pl[c];
            float f0[16], f1[16], f2[16];
            float sa0 = 0.f, sa1 = 0.f, sa2 = 0.f, sa3 = 0.f;
            float sb0 = 0.f, sb1 = 0.f, sb2 = 0.f, sb3 = 0.f;
            if (rr == 0) {
                LOADP(f0, 2, 0) LOADP(f1, 0, 4) LOADP(f2, 1, 4)
                TAPS(f0, 3, 0, 10) TAPS(f1, 0, 1, 10) TAPS(f2, 0, 2, 9)
            } else if (rr == 1) {
                LOADP(f0, 1, -332) LOADP(f1, 2, -332) LOADP(f2, 0, -332)
                TAPS(f0, 2, 0, 10) TAPS(f1, 2, 1, 10) TAPS(f2, 3, 2, 9)
            } else {
                LOADP(f0, 0, -664) LOADP(f1, 1, -664) LOADP(f2, 2, -664)
                TAPS(f0, 1, 0, 10) TAPS(f1, 1, 1, 10) TAPS(f2, 1, 2, 9)
            }
            const float swA = sws6[nb0][c], swB = sws6[nb1][c];
            aA0 += fmaxf(fmaf(sa0, scA, biA), 0.f) * swA;
            aA1 += fmaxf(fmaf(sa1, scA, biA), 0.f) * swA;
            aA2 += fmaxf(fmaf(sa2, scA, biA), 0.f) * swA;
            aA3 += fmaxf(fmaf(sa3, scA, biA), 0.f) * swA;
            aB0 += fmaxf(fmaf(sb0, scB, biB), 0.f) * swB;
            aB1 += fmaxf(fmaf(sb1, scB, biB), 0.f) * swB;
            aB2 += fmaxf(fmaf(sb2, scB, biB), 0.f) * swB;
            aB3 += fmaxf(fmaf(sb3, scB, biB), 0.f) * swB;
        }
        *(float4*)&hrow[nb0][4*tile] = make_float4(aA0, aA1, aA2, aA3);
        *(float4*)&hrow[nb1][4*tile] = make_float4(aB0, aB1, aB2, aB3);
    }
    __syncthreads();
    if (tid < 36) {    // substitute exact special outputs
        const int nb = tid / 6, tix = tid % 6;
        const int t = (tix == 0) ? 0 :
                      (tix <= 2) ? (331 + tix) :        // 332, 333
                      (tix <= 4) ? (663 + tix) : 999;   // 666, 667
        hrow[nb][t] = corr[nb][tix];
    }
    __syncthreads();

    // ---- pooling: 48 windows x 8 threads ----
    if (tid < 384) {
        const int w = tid >> 3, jj = tid & 7;
        const int nb = w >> 3, p = w & 7;
        float s = 0.f;
        for (int k = jj; k < POOL_; k += 8) s += hrow[nb][p*POOL_ + k];
        s += __shfl_down(s, 4, 8);
        s += __shfl_down(s, 2, 8);
        s += __shfl_down(s, 1, 8);
        if (jj == 0) { psum[w] = s; hpl[w] = s * (1.f / POOL_); }
    }
    __syncthreads();
    if (tid < NB_) {
        float s = 0.f;
        for (int p = 0; p < TP_; ++p) s += psum[tid*TP_ + p];
        gms[tid] = s * (1.f / T_);
    }
    __syncthreads();

    // ---- stage2: gate logits ----
    if (tid < MNB_) {
        float s = gate_b[tid];
        for (int c = 0; c < NB_; ++c) s += gms[c] * gate_w[tid*NB_ + c];
        lg[tid] = s;
    }
    __syncthreads();
    if (tid == 0) {
        float mx = lg[0];
        for (int i = 1; i < MNB_; ++i) mx = fmaxf(mx, lg[i]);
        for (int i = 0; i < MNB_; ++i) lg[i] = expf(lg[i] - mx);
        int i1 = 0, i2 = -1, i3 = -1;
        float b1 = -1.f, b2 = -1.f, b3 = -1.f;
        for (int i = 0; i < MNB_; ++i) if (lg[i] > b1) { b1 = lg[i]; i1 = i; }
        for (int i = 0; i < MNB_; ++i) if (i != i1 && lg[i] > b2) { b2 = lg[i]; i2 = i; }
        for (int i = 0; i < MNB_; ++i) if (i != i1 && i != i2 && lg[i] > b3) { b3 = lg[i]; i3 = i; }
        const float s3 = lg[i1] + lg[i2] + lg[i3];
        for (int jj = 0; jj < E_; ++jj) gsh[jj] = 0.f;
        if (i1 < E_) gsh[i1] = lg[i1] / s3;
        if (i2 < E_) gsh[i2] = lg[i2] / s3;
        if (i3 < E_) gsh[i3] = lg[i3] / s3;
    }
    __syncthreads();

    // ---- experts + EBN + ReLU + gate-mix -> feats ----
    if (tid < FEAT_) {
        const int o = tid >> 3, p = tid & 7;
        float outv = 0.f;
        #pragma unroll
        for (int e = 0; e < E_; ++e) {
            const int eo = e*MNB_ + o;
            float acc = exp_b[eo];
            #pragma unroll
            for (int c = 0; c < NB_; ++c)
                acc += hpl[c*TP_ + p] * exp_w[eo*NB_ + c];
            const float esc = ebn_g[eo] * rsqrtf(ebn_v[eo] + 1e-5f);
            float v = fmaf(acc - ebn_m[eo], esc, ebn_b[eo]);
            v = fmaxf(v, 0.f);
            outv += gsh[e] * v;
        }
        fsh[tid] = outv;
        feats_out[b*FEAT_ + tid] = outv;
    }
    __syncthreads();

    // ---- FC: 9 classes x 8 partials ----
    if (tid < NC_ * 8) {
        const int cls = tid >> 3, part = tid & 7;
        float s = 0.f;
        const float* wr = fc_w + cls*FEAT_ + part*48;
        const float* fr = fsh + part*48;
        for (int i = 0; i < 48; ++i) s = fmaf(fr[i], wr[i], s);
        fpart[cls][part] = s;
    }
    __syncthreads();
    if (tid < NC_) {
        float s = fc_b[tid];
        for (int p = 0; p < 8; ++p) s += fpart[tid][p];
        lo[tid] = s;
    }
    __syncthreads();
    if (tid == 0) {
        float mx = lo[0];
        for (int k = 1; k < NC_; ++k) mx = fmaxf(mx, lo[k]);
        float Z = 0.f;
        for (int k = 0; k < NC_; ++k) Z += expf(lo[k] - mx);
        const float lse = mx + logf(Z);
        for (int k = 0; k < NC_; ++k) logp_out[b*NC_ + k] = lo[k] - lse;
    }
}

extern "C" void kernel_launch(void* const* d_in, const int* in_sizes, int n_in,
                              void* d_out, int out_size, void* d_ws, size_t ws_size,
                              hipStream_t stream) {
    const float* x       = (const float*)d_in[0];
    const float* fir     = (const float*)d_in[1];
    const float* w3      = (const float*)d_in[2];
    const float* w5      = (const float*)d_in[3];
    const float* w7      = (const float*)d_in[4];
    const float* bn1_g   = (const float*)d_in[5];
    const float* bn1_b   = (const float*)d_in[6];
    const float* bn1_m   = (const float*)d_in[7];
    const float* bn1_v   = (const float*)d_in[8];
    const float* sconv_w = (const float*)d_in[9];
    const float* gate_w  = (const float*)d_in[10];
    const float* gate_b  = (const float*)d_in[11];
    const float* exp_w   = (const float*)d_in[12];
    const float* exp_b   = (const float*)d_in[13];
    const float* ebn_g   = (const float*)d_in[14];
    const float* ebn_b   = (const float*)d_in[15];
    const float* ebn_m   = (const float*)d_in[16];
    const float* ebn_v   = (const float*)d_in[17];
    const float* fc_w    = (const float*)d_in[18];
    const float* fc_b    = (const float*)d_in[19];

    float* out       = (float*)d_out;
    float* feats_out = out;                     // (256, 384)
    float* logp_out  = out + B_ * FEAT_;        // (256, 9)

    fb_fused<<<B_, NTH, 0, stream>>>(x, fir, w3, w5, w7,
                                     bn1_g, bn1_b, bn1_m, bn1_v, sconv_w,
                                     gate_w, gate_b, exp_w, exp_b,
                                     ebn_g, ebn_b, ebn_m, ebn_v,
                                     fc_w, fc_b, feats_out, logp_out);
}